// Round 5
// baseline (275.759 us; speedup 1.0000x reference)
//
#include <hip/hip_runtime.h>
#include <hip/hip_bf16.h>
#include <hip/hip_cooperative_groups.h>

namespace cg = cooperative_groups;

#define D_MODEL 1024
#define D_STATE 16
#define DT_RANK 64
#define SEQ 2048
#define BATCH 2
#define M_TOTAL 4096
#define CHUNKS 64
#define CLEN 32
#define LOG2E 1.44269504088896f

typedef __bf16 bf16x8 __attribute__((ext_vector_type(8)));
typedef float f32x4 __attribute__((ext_vector_type(4)));

__device__ __forceinline__ unsigned short f2bf(float f) {
    union { float f; unsigned int u; } v; v.f = f;
    unsigned int r = v.u + 0x7FFFu + ((v.u >> 16) & 1u);
    return (unsigned short)(r >> 16);
}
__device__ __forceinline__ float bf2f(unsigned short u) {
    union { unsigned int i; float f; } v; v.i = ((unsigned int)u) << 16; return v.f;
}
__device__ __forceinline__ void gload16(const void* g, void* l) {
    __builtin_amdgcn_global_load_lds(
        (const __attribute__((address_space(1))) unsigned int*)g,
        (__attribute__((address_space(3))) unsigned int*)l, 16, 0, 0);
}
__device__ __forceinline__ float fexp2(float x) { return __builtin_amdgcn_exp2f(x); }

// ---------- fused setup ----------
__global__ void __launch_bounds__(256) k_setup(const float* __restrict__ x,
                                               const float* __restrict__ win,
                                               const float* __restrict__ wx,
                                               const float* __restrict__ wdt,
                                               const float* __restrict__ alog,
                                               unsigned short* __restrict__ xb,
                                               unsigned short* __restrict__ bt,
                                               unsigned short* __restrict__ wxT,
                                               unsigned short* __restrict__ wxBC,
                                               unsigned short* __restrict__ wdtT,
                                               float* __restrict__ aneg,
                                               unsigned short* __restrict__ anegT) {
    __shared__ float tile[32][33];
    int blk = blockIdx.x;
    int t = threadIdx.x;
    if (blk < 4096) {  // x -> bf16
        int i = blk * 256 + t;
        float4 v = reinterpret_cast<const float4*>(x)[i];
        ushort4 o;
        o.x = f2bf(v.x); o.y = f2bf(v.y); o.z = f2bf(v.z); o.w = f2bf(v.w);
        reinterpret_cast<ushort4*>(xb)[i] = o;
    } else if (blk < 5120) {  // w_in^T -> bt
        int blk2 = blk - 4096;
        int bx = blk2 & 31, by = blk2 >> 5;
        int tx = t & 31, ty = t >> 5;
        int xc = bx * 32 + tx;
#pragma unroll
        for (int j = 0; j < 4; j++)
            tile[ty + 8 * j][tx] = win[(by * 32 + ty + 8 * j) * D_MODEL + xc];
        __syncthreads();
        int x2 = by * 32 + tx;
#pragma unroll
        for (int j = 0; j < 4; j++)
            bt[(bx * 32 + ty + 8 * j) * D_MODEL + x2] = f2bf(tile[tx][ty + 8 * j]);
    } else if (blk < 5376) {  // wxT[p][e] = w_x[e][p], p<64
        int idx = (blk - 5120) * 256 + t;
        int e = idx & 1023, p = idx >> 10;
        wxT[p * D_MODEL + e] = f2bf(wx[e * 96 + p]);
    } else if (blk < 5504) {  // wxBC[p][e] = w_x[e][64+p], p<32
        int idx = (blk - 5376) * 256 + t;
        int e = idx & 1023, p = idx >> 10;
        wxBC[p * D_MODEL + e] = f2bf(wx[e * 96 + 64 + p]);
    } else if (blk < 5568) {  // aneg (fp32, [d][n], pre-scaled by log2e) + anegT (bf16, [n][d], UNscaled)
        int i = (blk - 5504) * 256 + t;  // 64 blocks -> 16384 exact
        float v = -expf(alog[i]);
        aneg[i] = v * LOG2E;
        anegT[(i & 15) * D_MODEL + (i >> 4)] = f2bf(v);
    } else {  // wdtT[d][k] = w_dt[k][d] bf16  (256 blocks -> 65536)
        int idx = (blk - 5568) * 256 + t;
        int d = idx & 1023, k = idx >> 10;
        wdtT[d * DT_RANK + k] = f2bf(wdt[k * D_MODEL + d]);
    }
}

// ---------- x_in GEMM: x_in = x @ w_in. 64x128 tile, BK=64, dbuf, XOR-swizzle, grid 512 ----------
__global__ void __launch_bounds__(256) k_gemm_xin(const unsigned short* __restrict__ xb,
                                                  const unsigned short* __restrict__ bt,
                                                  unsigned short* __restrict__ xinb) {
    __shared__ unsigned short sA[2][64 * 64];
    __shared__ unsigned short sB[2][128 * 64];
    int bid = blockIdx.x;        // 512 = 64 m-tiles x 8 n-tiles
    int m0 = (bid & 63) * 64;
    int n0 = (bid >> 6) * 128;
    int t = threadIdx.x;
    int lane = t & 63;
    int w = t >> 6;
    int wm = (w >> 1) * 32, wn = (w & 1) * 64;
    int c = lane & 15, q = lane >> 4;

    const unsigned short* gA[2];
    const unsigned short* gB[4];
#pragma unroll
    for (int L = 0; L < 2; L++) {
        int s = L * 256 + t;
        int row = s >> 3, ch = (s & 7) ^ (row & 7);
        gA[L] = xb + (m0 + row) * D_MODEL + ch * 8;
    }
#pragma unroll
    for (int L = 0; L < 4; L++) {
        int s = L * 256 + t;
        int row = s >> 3, ch = (s & 7) ^ (row & 7);
        gB[L] = bt + (n0 + row) * D_MODEL + ch * 8;
    }

    f32x4 acc[2][4] = {};
    {
        char* la = (char*)&sA[0][0] + w * 1024;
        char* lb = (char*)&sB[0][0] + w * 1024;
#pragma unroll
        for (int L = 0; L < 2; L++) gload16(gA[L], la + L * 4096);
#pragma unroll
        for (int L = 0; L < 4; L++) gload16(gB[L], lb + L * 4096);
    }
    int cur = 0;
    for (int it = 0; it < 16; it++) {
        __syncthreads();
        if (it + 1 < 16) {
            int kn = (it + 1) * 64;
            char* la = (char*)&sA[cur ^ 1][0] + w * 1024;
            char* lb = (char*)&sB[cur ^ 1][0] + w * 1024;
#pragma unroll
            for (int L = 0; L < 2; L++) gload16(gA[L] + kn, la + L * 4096);
#pragma unroll
            for (int L = 0; L < 4; L++) gload16(gB[L] + kn, lb + L * 4096);
        }
#pragma unroll
        for (int kk = 0; kk < 2; kk++) {
            int perm = (((kk << 2) | q) ^ (c & 7)) << 3;
            bf16x8 af[2], bfr[4];
#pragma unroll
            for (int i = 0; i < 2; i++)
                af[i] = *reinterpret_cast<const bf16x8*>(&sA[cur][(wm + i * 16 + c) * 64 + perm]);
#pragma unroll
            for (int j = 0; j < 4; j++)
                bfr[j] = *reinterpret_cast<const bf16x8*>(&sB[cur][(wn + j * 16 + c) * 64 + perm]);
            // swapped operands: lane owns 4 consecutive n-cols
#pragma unroll
            for (int i = 0; i < 2; i++)
#pragma unroll
                for (int j = 0; j < 4; j++)
                    acc[i][j] = __builtin_amdgcn_mfma_f32_16x16x32_bf16(bfr[j], af[i], acc[i][j], 0, 0, 0);
        }
        cur ^= 1;
    }
#pragma unroll
    for (int i = 0; i < 2; i++) {
        int row = m0 + wm + i * 16 + c;
#pragma unroll
        for (int j = 0; j < 4; j++) {
            int col = n0 + wn + j * 16 + q * 4;
            ushort4 o;
            o.x = f2bf(acc[i][j][0]); o.y = f2bf(acc[i][j][1]);
            o.z = f2bf(acc[i][j][2]); o.w = f2bf(acc[i][j][3]);
            *reinterpret_cast<ushort4*>(&xinb[row * D_MODEL + col]) = o;
        }
    }
}

// ---------- x_low: full-K reduction, bf16 out. xlow[m][p] = sum_k x_in[m][k] wxT[p][k] ----------
__global__ void __launch_bounds__(256) k_xlow(const unsigned short* __restrict__ xinb,
                                              const unsigned short* __restrict__ wxT,
                                              unsigned short* __restrict__ xlow) {
    int m0 = blockIdx.x * 64;  // 64 blocks x 64 rows
    int t = threadIdx.x;
    int lane = t & 63, w = t >> 6;
    int c = lane & 15, q = lane >> 4;
    int row = m0 + w * 16 + c;
    f32x4 acc[4] = {};
    const unsigned short* pa = xinb + row * D_MODEL + q * 8;
    const unsigned short* pw = wxT + c * D_MODEL + q * 8;
#pragma unroll 4
    for (int k0 = 0; k0 < D_MODEL; k0 += 32) {
        bf16x8 a0 = *reinterpret_cast<const bf16x8*>(pa + k0);
#pragma unroll
        for (int j = 0; j < 4; j++) {
            bf16x8 wf = *reinterpret_cast<const bf16x8*>(pw + j * 16 * D_MODEL + k0);
            acc[j] = __builtin_amdgcn_mfma_f32_16x16x32_bf16(wf, a0, acc[j], 0, 0, 0);
        }
    }
    // swapped C/D: lane col(c) = m-row, rows q*4+r = p -> 8B bf16 stores
#pragma unroll
    for (int j = 0; j < 4; j++) {
        ushort4 o;
        o.x = f2bf(acc[j][0]); o.y = f2bf(acc[j][1]);
        o.z = f2bf(acc[j][2]); o.w = f2bf(acc[j][3]);
        *reinterpret_cast<ushort4*>(&xlow[row * DT_RANK + j * 16 + q * 4]) = o;
    }
}

// ---------- dt GEMM: dt = softplus(x_low @ w_dt + b_dt) scaled; K=64, bf16 A staged via gload16 ----------
__global__ void __launch_bounds__(256) k_gemm_dt(const unsigned short* __restrict__ xlow,
                                                 const unsigned short* __restrict__ wdtT,
                                                 const float* __restrict__ bdt,
                                                 unsigned short* __restrict__ dtb) {
    __shared__ unsigned short sA[128 * 64];
    int bid = blockIdx.x;  // 256 = 32 m x 8 n
    int m0 = (bid & 31) * 128;
    int n0 = (bid >> 5) * 128;
    int t = threadIdx.x;
    int lane = t & 63, w = t >> 6;
    int c = lane & 15, q = lane >> 4;

    // stage A tile (128 rows x 64 k bf16) with pre-swizzled SOURCE, linear LDS dest
    {
        char* la = (char*)&sA[0] + w * 1024;
#pragma unroll
        for (int L = 0; L < 4; L++) {
            int s = L * 256 + t;
            int row = s >> 3, ch = (s & 7) ^ (row & 7);
            gload16(xlow + (m0 + row) * DT_RANK + ch * 8, la + L * 4096);
        }
    }
    __syncthreads();

    int mw = m0 + w * 32;
    f32x4 acc[2][8] = {};
#pragma unroll
    for (int kk = 0; kk < 2; kk++) {
        bf16x8 af[2];
#pragma unroll
        for (int i = 0; i < 2; i++)
            af[i] = *reinterpret_cast<const bf16x8*>(
                &sA[(w * 32 + i * 16 + c) * 64 + ((((kk << 2) | q)) ^ (c & 7)) * 8]);
#pragma unroll
        for (int j = 0; j < 8; j++) {
            bf16x8 bfr = *reinterpret_cast<const bf16x8*>(
                &wdtT[(n0 + j * 16 + c) * DT_RANK + kk * 32 + q * 8]);
            acc[0][j] = __builtin_amdgcn_mfma_f32_16x16x32_bf16(bfr, af[0], acc[0][j], 0, 0, 0);
            acc[1][j] = __builtin_amdgcn_mfma_f32_16x16x32_bf16(bfr, af[1], acc[1][j], 0, 0, 0);
        }
    }
    // epilogue: softplus -> dtb (swapped C/D: lane owns 4 consecutive d)
#pragma unroll
    for (int i = 0; i < 2; i++) {
        int row = mw + i * 16 + c;
#pragma unroll
        for (int j = 0; j < 8; j++) {
            int dcol = n0 + j * 16 + q * 4;
            float4 bv = *reinterpret_cast<const float4*>(&bdt[dcol]);
            ushort4 o;
            {
                float xv = acc[i][j][0] + bv.x;
                float sp = fmaxf(xv, 0.f) + __logf(1.f + __expf(-fabsf(xv)));
                o.x = f2bf(sp * 0.099f + 0.001f);
            }
            {
                float xv = acc[i][j][1] + bv.y;
                float sp = fmaxf(xv, 0.f) + __logf(1.f + __expf(-fabsf(xv)));
                o.y = f2bf(sp * 0.099f + 0.001f);
            }
            {
                float xv = acc[i][j][2] + bv.z;
                float sp = fmaxf(xv, 0.f) + __logf(1.f + __expf(-fabsf(xv)));
                o.z = f2bf(sp * 0.099f + 0.001f);
            }
            {
                float xv = acc[i][j][3] + bv.w;
                float sp = fmaxf(xv, 0.f) + __logf(1.f + __expf(-fabsf(xv)));
                o.w = f2bf(sp * 0.099f + 0.001f);
            }
            *reinterpret_cast<ushort4*>(&dtb[row * D_MODEL + dcol]) = o;
        }
    }
}

// ---------- cooperative tail: bcw -> scan1 -> scan2 -> scan3, one launch ----------
// grid 256 x 512thr, each block = two 256-thr "virtual blocks" (ob = bid*2 + half)
__global__ void __launch_bounds__(512) k_tail(const unsigned short* __restrict__ dtb,
                                              const unsigned short* __restrict__ xinb,
                                              const unsigned short* __restrict__ wxBC,
                                              const unsigned short* __restrict__ anegT,
                                              const float* __restrict__ aneg,
                                              const float* __restrict__ dp,
                                              float* __restrict__ bcp,
                                              float* __restrict__ wpp,
                                              float* __restrict__ h_loc,
                                              float* __restrict__ dtsum,
                                              float* __restrict__ out) {
    cg::grid_group grid = cg::this_grid();
    __shared__ unsigned short s_dt[2][16][256];
    __shared__ unsigned short s_u[2][16][256];
    __shared__ float s_w[2][16][16];
    __shared__ float s_c[2][16][16];

    int tid = threadIdx.x;
    int half = tid >> 8;
    int lt = tid & 255;
    int ob = blockIdx.x * 2 + half;   // 0..511
    int lane = lt & 63;
    int c16 = lane & 15, q = lane >> 4;

    // ---- Phase A: BCW GEMM (ob = 64 mtiles x 8 ksplit; 16 rows per wave) ----
    {
        int m0 = (ob & 63) * 64;
        int ks = ob >> 6;
        int kbase = ks * 128;
        int w2 = lt >> 6;             // wave within half
        int mw = m0 + w2 * 16;
        f32x4 accb[2] = {};
        f32x4 accw = {};
        const unsigned short* pa = xinb + (mw + c16) * D_MODEL + kbase + q * 8;
        const unsigned short* pt = dtb + (mw + c16) * D_MODEL + kbase + q * 8;
        const unsigned short* pb0 = wxBC + c16 * D_MODEL + kbase + q * 8;
        const unsigned short* pb1 = pb0 + 16 * D_MODEL;
        const unsigned short* pA = anegT + c16 * D_MODEL + kbase + q * 8;
#pragma unroll
        for (int k0 = 0; k0 < 128; k0 += 32) {
            bf16x8 a0 = *reinterpret_cast<const bf16x8*>(pa + k0);
            bf16x8 t0 = *reinterpret_cast<const bf16x8*>(pt + k0);
            bf16x8 b0 = *reinterpret_cast<const bf16x8*>(pb0 + k0);
            bf16x8 b1 = *reinterpret_cast<const bf16x8*>(pb1 + k0);
            bf16x8 bA = *reinterpret_cast<const bf16x8*>(pA + k0);
            bf16x8 g0;
#pragma unroll
            for (int e = 0; e < 8; e++) g0[e] = (__bf16)((float)t0[e] * (float)a0[e]);
            accb[0] = __builtin_amdgcn_mfma_f32_16x16x32_bf16(b0, a0, accb[0], 0, 0, 0);
            accb[1] = __builtin_amdgcn_mfma_f32_16x16x32_bf16(b1, a0, accb[1], 0, 0, 0);
            accw = __builtin_amdgcn_mfma_f32_16x16x32_bf16(bA, g0, accw, 0, 0, 0);
        }
        int row = mw + c16;  // swapped C/D: lane col = m-row
#pragma unroll
        for (int j = 0; j < 2; j++)
            *reinterpret_cast<f32x4*>(&bcp[(ks * M_TOTAL + row) * 32 + j * 16 + q * 4]) = accb[j];
        *reinterpret_cast<f32x4*>(&wpp[(ks * M_TOTAL + row) * 16 + q * 4]) = accw;
    }
    grid.sync();

    // common scan mapping for phases B/D
    int dc = ob & 3;
    int cch = (ob >> 2) & (CHUNKS - 1);
    int bb = ob >> 8;
    int d = dc * 256 + lt;
    int r8 = lt >> 5, col8 = (lt & 31) * 8;

    // ---- Phase B: chunk-local scan -> h_loc, dtsum ----
    {
        float Ad[16];
        const float4* ar = reinterpret_cast<const float4*>(aneg + d * 16);
#pragma unroll
        for (int j = 0; j < 4; j++) {
            float4 a4 = ar[j];
            Ad[4 * j + 0] = a4.x; Ad[4 * j + 1] = a4.y;
            Ad[4 * j + 2] = a4.z; Ad[4 * j + 3] = a4.w;
        }
        float h[16];
#pragma unroll
        for (int n = 0; n < 16; n++) h[n] = 0.f;
        float dts = 0.f;
        for (int t0 = 0; t0 < CLEN; t0 += 16) {
            __syncthreads();
            int rowbase = bb * SEQ + cch * CLEN + t0;
            *reinterpret_cast<uint4*>(&s_dt[half][r8][col8]) =
                *reinterpret_cast<const uint4*>(dtb + (rowbase + r8) * D_MODEL + dc * 256 + col8);
            *reinterpret_cast<uint4*>(&s_dt[half][8 + r8][col8]) =
                *reinterpret_cast<const uint4*>(dtb + (rowbase + 8 + r8) * D_MODEL + dc * 256 + col8);
            {
                int r = lt >> 4, n = lt & 15;
                int row = rowbase + r;
                float sB = 0.f, sw = 0.f;
#pragma unroll
                for (int ks = 0; ks < 8; ks++) {
                    sB += bcp[(ks * M_TOTAL + row) * 32 + n];
                    sw += wpp[(ks * M_TOTAL + row) * 16 + n];
                }
                s_w[half][r][n] = sB * sw;
            }
            __syncthreads();
            for (int r = 0; r < 16; r++) {
                float dtv = bf2f(s_dt[half][r][lt]);
                dts += dtv;
#pragma unroll
                for (int n = 0; n < 16; n++) {
                    float ba = fexp2(dtv * Ad[n]);  // Ad pre-scaled by log2e
                    h[n] = fmaf(ba, h[n], s_w[half][r][n]);
                }
            }
        }
        int base = ((bb * CHUNKS + cch) * D_MODEL + d) * 16;
#pragma unroll
        for (int j = 0; j < 4; j++) {
            f32x4 v = {h[4 * j], h[4 * j + 1], h[4 * j + 2], h[4 * j + 3]};
            *reinterpret_cast<f32x4*>(h_loc + base + 4 * j) = v;
        }
        dtsum[(bb * CHUNKS + cch) * D_MODEL + d] = dts;
    }
    grid.sync();

    // ---- Phase C: combine chunks (first 32768 threads), 8-deep prefetch ----
    {
        int idx = blockIdx.x * 512 + tid;
        if (idx < 32768) {
            int n = idx & 15;
            int dd = (idx >> 4) & (D_MODEL - 1);
            int b2 = idx >> 14;
            float A = aneg[dd * 16 + n];  // pre-scaled by log2e
            float H = 0.f;
            int off0 = b2 * CHUNKS * D_MODEL + dd;
#pragma unroll 1
            for (int g = 0; g < CHUNKS; g += 8) {
                float hl[8], ds[8];
#pragma unroll
                for (int j = 0; j < 8; j++) {
                    int off = off0 + (g + j) * D_MODEL;
                    hl[j] = h_loc[off * 16 + n];
                    ds[j] = dtsum[off];
                }
#pragma unroll
                for (int j = 0; j < 8; j++) {
                    int off = off0 + (g + j) * D_MODEL;
                    float P = fexp2(ds[j] * A);
                    h_loc[off * 16 + n] = H;
                    H = fmaf(P, H, hl[j]);
                }
            }
        }
    }
    grid.sync();

    // ---- Phase D: chunk scan from H_in; emit y ----
    {
        float Ad[16];
        const float4* ar = reinterpret_cast<const float4*>(aneg + d * 16);
#pragma unroll
        for (int j = 0; j < 4; j++) {
            float4 a4 = ar[j];
            Ad[4 * j + 0] = a4.x; Ad[4 * j + 1] = a4.y;
            Ad[4 * j + 2] = a4.z; Ad[4 * j + 3] = a4.w;
        }
        float Dpd = dp[d];
        float h[16];
        int base = ((bb * CHUNKS + cch) * D_MODEL + d) * 16;
#pragma unroll
        for (int j = 0; j < 4; j++) {
            f32x4 v = *reinterpret_cast<const f32x4*>(h_loc + base + 4 * j);
            h[4 * j] = v[0]; h[4 * j + 1] = v[1]; h[4 * j + 2] = v[2]; h[4 * j + 3] = v[3];
        }
        for (int t0 = 0; t0 < CLEN; t0 += 16) {
            __syncthreads();
            int rowbase = bb * SEQ + cch * CLEN + t0;
            *reinterpret_cast<uint4*>(&s_dt[half][r8][col8]) =
                *reinterpret_cast<const uint4*>(dtb + (rowbase + r8) * D_MODEL + dc * 256 + col8);
            *reinterpret_cast<uint4*>(&s_dt[half][8 + r8][col8]) =
                *reinterpret_cast<const uint4*>(dtb + (rowbase + 8 + r8) * D_MODEL + dc * 256 + col8);
            *reinterpret_cast<uint4*>(&s_u[half][r8][col8]) =
                *reinterpret_cast<const uint4*>(xinb + (rowbase + r8) * D_MODEL + dc * 256 + col8);
            *reinterpret_cast<uint4*>(&s_u[half][8 + r8][col8]) =
                *reinterpret_cast<const uint4*>(xinb + (rowbase + 8 + r8) * D_MODEL + dc * 256 + col8);
            {
                int r = lt >> 4, n = lt & 15;
                int row = rowbase + r;
                float sB = 0.f, sw = 0.f, sC = 0.f;
#pragma unroll
                for (int ks = 0; ks < 8; ks++) {
                    sB += bcp[(ks * M_TOTAL + row) * 32 + n];
                    sC += bcp[(ks * M_TOTAL + row) * 32 + 16 + n];
                    sw += wpp[(ks * M_TOTAL + row) * 16 + n];
                }
                s_w[half][r][n] = sB * sw;
                s_c[half][r][n] = sC;
            }
            __syncthreads();
            for (int r = 0; r < 16; r++) {
                float dtv = bf2f(s_dt[half][r][lt]), uv = bf2f(s_u[half][r][lt]);
                float y = Dpd * uv;
#pragma unroll
                for (int n = 0; n < 16; n++) {
                    float ba = fexp2(dtv * Ad[n]);  // Ad pre-scaled by log2e
                    h[n] = fmaf(ba, h[n], s_w[half][r][n]);
                    y = fmaf(h[n], s_c[half][r][n], y);
                }
                out[(rowbase + r) * D_MODEL + d] = y;
            }
        }
    }
}

extern "C" void kernel_launch(void* const* d_in, const int* in_sizes, int n_in,
                              void* d_out, int out_size, void* d_ws, size_t ws_size,
                              hipStream_t stream) {
    const float* x     = (const float*)d_in[0];
    const float* w_in  = (const float*)d_in[1];
    const float* w_x   = (const float*)d_in[2];
    const float* w_dt  = (const float*)d_in[3];
    const float* b_dt  = (const float*)d_in[4];
    const float* A_log = (const float*)d_in[5];
    const float* Dp    = (const float*)d_in[6];
    float* out = (float*)d_out;

    char* ws = (char*)d_ws;
    // footprint capped below proven-safe 39124992 B
    unsigned short* xb   = (unsigned short*)(ws + 0);          // 8 MB  (dead after gemm_xin)
    unsigned short* bt   = (unsigned short*)(ws + 8388608);    // 2 MB  w_in^T (dead after gemm_xin)
    unsigned short* xinb = (unsigned short*)(ws + 10485760);   // 8 MB
    unsigned short* dtb  = (unsigned short*)(ws + 18874368);   // 8 MB
    float* bcp           = (float*)(ws + 27262976);            // 4 MB  -> ends 31457280
    float* wpp           = (float*)(ws + 31457280);            // 2 MB  -> ends 33554432
    unsigned short* xlow = (unsigned short*)(ws + 33554432);   // 512 KB bf16 [4096][64] -> ends 34078720
    unsigned short* wxT  = (unsigned short*)(ws + 35651584);   // 128 KB
    unsigned short* wxBC = (unsigned short*)(ws + 35782656);   // 64 KB
    unsigned short* wdtT = (unsigned short*)(ws + 35848192);   // 128 KB
    float* aneg          = (float*)(ws + 35979264);            // 64 KB (pre-scaled by log2e)
    unsigned short* anegT= (unsigned short*)(ws + 36044800);   // 32 KB -> ends 36077568
    // scan-phase overlays of dead xb/bt regions:
    float* h_loc         = (float*)(ws + 0);                   // 8 MB  [b][c][d][n]
    float* dtsum         = (float*)(ws + 8388608);             // 512 KB [b][c][d]

    k_setup<<<5824, 256, 0, stream>>>(x, w_in, w_x, w_dt, A_log, xb, bt, wxT, wxBC, wdtT, aneg, anegT);
    k_gemm_xin<<<512, 256, 0, stream>>>(xb, bt, xinb);
    k_xlow<<<64, 256, 0, stream>>>(xinb, wxT, xlow);
    k_gemm_dt<<<256, 256, 0, stream>>>(xlow, wdtT, b_dt, dtb);
    {
        const unsigned short* a0 = dtb;
        const unsigned short* a1 = xinb;
        const unsigned short* a2 = wxBC;
        const unsigned short* a3 = anegT;
        const float* a4 = aneg;
        const float* a5 = Dp;
        float* a6 = bcp;
        float* a7 = wpp;
        float* a8 = h_loc;
        float* a9 = dtsum;
        float* a10 = out;
        void* args[] = {&a0, &a1, &a2, &a3, &a4, &a5, &a6, &a7, &a8, &a9, &a10};
        hipLaunchCooperativeKernel((const void*)k_tail, dim3(256), dim3(512), args, 0, stream);
    }
}

// Round 6
// 204.025 us; speedup vs baseline: 1.3516x; 1.3516x over previous
//
#include <hip/hip_runtime.h>
#include <hip/hip_bf16.h>

#define D_MODEL 1024
#define D_STATE 16
#define DT_RANK 64
#define SEQ 2048
#define BATCH 2
#define M_TOTAL 4096
#define CHUNKS 64
#define CLEN 32
#define LOG2E 1.44269504088896f

typedef __bf16 bf16x8 __attribute__((ext_vector_type(8)));
typedef float f32x4 __attribute__((ext_vector_type(4)));

__device__ __forceinline__ unsigned short f2bf(float f) {
    union { float f; unsigned int u; } v; v.f = f;
    unsigned int r = v.u + 0x7FFFu + ((v.u >> 16) & 1u);
    return (unsigned short)(r >> 16);
}
__device__ __forceinline__ float bf2f(unsigned short u) {
    union { unsigned int i; float f; } v; v.i = ((unsigned int)u) << 16; return v.f;
}
__device__ __forceinline__ void gload16(const void* g, void* l) {
    __builtin_amdgcn_global_load_lds(
        (const __attribute__((address_space(1))) unsigned int*)g,
        (__attribute__((address_space(3))) unsigned int*)l, 16, 0, 0);
}
__device__ __forceinline__ float fexp2(float x) { return __builtin_amdgcn_exp2f(x); }

// ---------- fused setup ----------
__global__ void __launch_bounds__(256) k_setup(const float* __restrict__ x,
                                               const float* __restrict__ win,
                                               const float* __restrict__ wx,
                                               const float* __restrict__ wdt,
                                               const float* __restrict__ alog,
                                               unsigned short* __restrict__ xb,
                                               unsigned short* __restrict__ bt,
                                               unsigned short* __restrict__ wxT,
                                               unsigned short* __restrict__ wxBC,
                                               unsigned short* __restrict__ wdtT,
                                               float* __restrict__ aneg,
                                               unsigned short* __restrict__ anegT) {
    __shared__ float tile[32][33];
    int blk = blockIdx.x;
    int t = threadIdx.x;
    if (blk < 4096) {  // x -> bf16
        int i = blk * 256 + t;
        float4 v = reinterpret_cast<const float4*>(x)[i];
        ushort4 o;
        o.x = f2bf(v.x); o.y = f2bf(v.y); o.z = f2bf(v.z); o.w = f2bf(v.w);
        reinterpret_cast<ushort4*>(xb)[i] = o;
    } else if (blk < 5120) {  // w_in^T -> bt
        int blk2 = blk - 4096;
        int bx = blk2 & 31, by = blk2 >> 5;
        int tx = t & 31, ty = t >> 5;
        int xc = bx * 32 + tx;
#pragma unroll
        for (int j = 0; j < 4; j++)
            tile[ty + 8 * j][tx] = win[(by * 32 + ty + 8 * j) * D_MODEL + xc];
        __syncthreads();
        int x2 = by * 32 + tx;
#pragma unroll
        for (int j = 0; j < 4; j++)
            bt[(bx * 32 + ty + 8 * j) * D_MODEL + x2] = f2bf(tile[tx][ty + 8 * j]);
    } else if (blk < 5376) {  // wxT[p][e] = w_x[e][p], p<64
        int idx = (blk - 5120) * 256 + t;
        int e = idx & 1023, p = idx >> 10;
        wxT[p * D_MODEL + e] = f2bf(wx[e * 96 + p]);
    } else if (blk < 5504) {  // wxBC[p][e] = w_x[e][64+p], p<32
        int idx = (blk - 5376) * 256 + t;
        int e = idx & 1023, p = idx >> 10;
        wxBC[p * D_MODEL + e] = f2bf(wx[e * 96 + 64 + p]);
    } else if (blk < 5568) {  // aneg (fp32, [d][n], pre-scaled by log2e) + anegT (bf16, [n][d], UNscaled)
        int i = (blk - 5504) * 256 + t;  // 64 blocks -> 16384 exact
        float v = -expf(alog[i]);
        aneg[i] = v * LOG2E;
        anegT[(i & 15) * D_MODEL + (i >> 4)] = f2bf(v);
    } else {  // wdtT[d][k] = w_dt[k][d] bf16  (256 blocks -> 65536)
        int idx = (blk - 5568) * 256 + t;
        int d = idx & 1023, k = idx >> 10;
        wdtT[d * DT_RANK + k] = f2bf(wdt[k * D_MODEL + d]);
    }
}

// ---------- x_in GEMM: x_in = x @ w_in. 64x128 tile, BK=64, dbuf, XOR-swizzle, grid 512 ----------
__global__ void __launch_bounds__(256) k_gemm_xin(const unsigned short* __restrict__ xb,
                                                  const unsigned short* __restrict__ bt,
                                                  unsigned short* __restrict__ xinb) {
    __shared__ unsigned short sA[2][64 * 64];
    __shared__ unsigned short sB[2][128 * 64];
    int bid = blockIdx.x;        // 512 = 64 m-tiles x 8 n-tiles
    int m0 = (bid & 63) * 64;
    int n0 = (bid >> 6) * 128;
    int t = threadIdx.x;
    int lane = t & 63;
    int w = t >> 6;
    int wm = (w >> 1) * 32, wn = (w & 1) * 64;
    int c = lane & 15, q = lane >> 4;

    const unsigned short* gA[2];
    const unsigned short* gB[4];
#pragma unroll
    for (int L = 0; L < 2; L++) {
        int s = L * 256 + t;
        int row = s >> 3, ch = (s & 7) ^ (row & 7);
        gA[L] = xb + (m0 + row) * D_MODEL + ch * 8;
    }
#pragma unroll
    for (int L = 0; L < 4; L++) {
        int s = L * 256 + t;
        int row = s >> 3, ch = (s & 7) ^ (row & 7);
        gB[L] = bt + (n0 + row) * D_MODEL + ch * 8;
    }

    f32x4 acc[2][4] = {};
    {
        char* la = (char*)&sA[0][0] + w * 1024;
        char* lb = (char*)&sB[0][0] + w * 1024;
#pragma unroll
        for (int L = 0; L < 2; L++) gload16(gA[L], la + L * 4096);
#pragma unroll
        for (int L = 0; L < 4; L++) gload16(gB[L], lb + L * 4096);
    }
    int cur = 0;
    for (int it = 0; it < 16; it++) {
        __syncthreads();
        if (it + 1 < 16) {
            int kn = (it + 1) * 64;
            char* la = (char*)&sA[cur ^ 1][0] + w * 1024;
            char* lb = (char*)&sB[cur ^ 1][0] + w * 1024;
#pragma unroll
            for (int L = 0; L < 2; L++) gload16(gA[L] + kn, la + L * 4096);
#pragma unroll
            for (int L = 0; L < 4; L++) gload16(gB[L] + kn, lb + L * 4096);
        }
#pragma unroll
        for (int kk = 0; kk < 2; kk++) {
            int perm = (((kk << 2) | q) ^ (c & 7)) << 3;
            bf16x8 af[2], bfr[4];
#pragma unroll
            for (int i = 0; i < 2; i++)
                af[i] = *reinterpret_cast<const bf16x8*>(&sA[cur][(wm + i * 16 + c) * 64 + perm]);
#pragma unroll
            for (int j = 0; j < 4; j++)
                bfr[j] = *reinterpret_cast<const bf16x8*>(&sB[cur][(wn + j * 16 + c) * 64 + perm]);
            // swapped operands: lane owns 4 consecutive n-cols
#pragma unroll
            for (int i = 0; i < 2; i++)
#pragma unroll
                for (int j = 0; j < 4; j++)
                    acc[i][j] = __builtin_amdgcn_mfma_f32_16x16x32_bf16(bfr[j], af[i], acc[i][j], 0, 0, 0);
        }
        cur ^= 1;
    }
#pragma unroll
    for (int i = 0; i < 2; i++) {
        int row = m0 + wm + i * 16 + c;
#pragma unroll
        for (int j = 0; j < 4; j++) {
            int col = n0 + wn + j * 16 + q * 4;
            ushort4 o;
            o.x = f2bf(acc[i][j][0]); o.y = f2bf(acc[i][j][1]);
            o.z = f2bf(acc[i][j][2]); o.w = f2bf(acc[i][j][3]);
            *reinterpret_cast<ushort4*>(&xinb[row * D_MODEL + col]) = o;
        }
    }
}

// ---------- fused dt: xlow (K=1024, in-reg) -> LDS -> dt = softplus(xlow @ w_dt + b) ----------
// 64 blocks x 256 thr; wave w owns rows [w*16, w*16+16) of its 64-row slab end-to-end.
__global__ void __launch_bounds__(256) k_dt(const unsigned short* __restrict__ xinb,
                                            const unsigned short* __restrict__ wxT,
                                            const unsigned short* __restrict__ wdtT,
                                            const float* __restrict__ bdt,
                                            unsigned short* __restrict__ dtb) {
    __shared__ unsigned short sX[64 * 64];  // xlow tile, XOR-swizzled 8-short chunks
    int m0 = blockIdx.x * 64;
    int t = threadIdx.x;
    int lane = t & 63, w = t >> 6;
    int c = lane & 15, q = lane >> 4;
    int lrow = w * 16 + c;
    int row = m0 + lrow;

    // phase 1: xlow[row][0..64) = x_in[row][:] @ wxT[p][:]^T  (swapped MFMA, full K)
    f32x4 acc[4] = {};
    const unsigned short* pa = xinb + row * D_MODEL + q * 8;
    const unsigned short* pw = wxT + c * D_MODEL + q * 8;
#pragma unroll 4
    for (int k0 = 0; k0 < D_MODEL; k0 += 32) {
        bf16x8 a0 = *reinterpret_cast<const bf16x8*>(pa + k0);
#pragma unroll
        for (int j = 0; j < 4; j++) {
            bf16x8 wf = *reinterpret_cast<const bf16x8*>(pw + j * 16 * D_MODEL + k0);
            acc[j] = __builtin_amdgcn_mfma_f32_16x16x32_bf16(wf, a0, acc[j], 0, 0, 0);
        }
    }
    // store to LDS: swapped C/D -> lane holds xlow[row][j*16+q*4 .. +4); XOR-swizzle 8-short chunks
#pragma unroll
    for (int j = 0; j < 4; j++) {
        int col = j * 16 + q * 4;
        int chunk = col >> 3, within = col & 7;  // within = 0 or 4
        int swz = chunk ^ (lrow & 7);
        ushort4 o;
        o.x = f2bf(acc[j][0]); o.y = f2bf(acc[j][1]);
        o.z = f2bf(acc[j][2]); o.w = f2bf(acc[j][3]);
        *reinterpret_cast<ushort4*>(&sX[lrow * 64 + swz * 8 + within]) = o;
    }
    __syncthreads();

    // phase 2: dt rows = softplus(xlow_rows @ wdtT^T + b). A-frags from LDS (once), 64 col-tiles.
    bf16x8 af[2];
#pragma unroll
    for (int kk = 0; kk < 2; kk++) {
        int chunk = kk * 4 + q;
        int swz = chunk ^ (lrow & 7);
        af[kk] = *reinterpret_cast<const bf16x8*>(&sX[lrow * 64 + swz * 8]);
    }
#pragma unroll 4
    for (int j = 0; j < 64; j++) {
        f32x4 a = {};
#pragma unroll
        for (int kk = 0; kk < 2; kk++) {
            bf16x8 bfr = *reinterpret_cast<const bf16x8*>(
                &wdtT[(j * 16 + c) * DT_RANK + kk * 32 + q * 8]);
            a = __builtin_amdgcn_mfma_f32_16x16x32_bf16(bfr, af[kk], a, 0, 0, 0);
        }
        int dcol = j * 16 + q * 4;
        float4 bv = *reinterpret_cast<const float4*>(&bdt[dcol]);
        ushort4 o;
        {
            float xv = a[0] + bv.x;
            float sp = fmaxf(xv, 0.f) + __logf(1.f + __expf(-fabsf(xv)));
            o.x = f2bf(sp * 0.099f + 0.001f);
        }
        {
            float xv = a[1] + bv.y;
            float sp = fmaxf(xv, 0.f) + __logf(1.f + __expf(-fabsf(xv)));
            o.y = f2bf(sp * 0.099f + 0.001f);
        }
        {
            float xv = a[2] + bv.z;
            float sp = fmaxf(xv, 0.f) + __logf(1.f + __expf(-fabsf(xv)));
            o.z = f2bf(sp * 0.099f + 0.001f);
        }
        {
            float xv = a[3] + bv.w;
            float sp = fmaxf(xv, 0.f) + __logf(1.f + __expf(-fabsf(xv)));
            o.w = f2bf(sp * 0.099f + 0.001f);
        }
        *reinterpret_cast<ushort4*>(&dtb[row * D_MODEL + dcol]) = o;
    }
}

// ---------- BCW GEMM: bcp = x_in @ wxBC^T ; wpp = (dt*u) @ anegT^T ; ksplit=8, grid 256 ----------
__global__ void __launch_bounds__(256) k_bcw(const unsigned short* __restrict__ xinb,
                                             const unsigned short* __restrict__ dtb,
                                             const unsigned short* __restrict__ wxBC,
                                             const unsigned short* __restrict__ anegT,
                                             float* __restrict__ bcp,
                                             float* __restrict__ wpp) {
    int bid = blockIdx.x;  // 256 = 32 mtiles x 8 ksplit
    int m0 = (bid & 31) * 128;
    int ks = bid >> 5;
    int kbase = ks * 128;
    int t = threadIdx.x;
    int lane = t & 63, w = t >> 6;
    int c = lane & 15, q = lane >> 4;
    int mw = m0 + w * 32;
    f32x4 accb[2][2] = {};
    f32x4 accw[2] = {};
    const unsigned short* pa0 = xinb + (mw + c) * D_MODEL + kbase + q * 8;
    const unsigned short* pa1 = pa0 + 16 * D_MODEL;
    const unsigned short* pt0 = dtb + (mw + c) * D_MODEL + kbase + q * 8;
    const unsigned short* pt1 = pt0 + 16 * D_MODEL;
    const unsigned short* pb0 = wxBC + c * D_MODEL + kbase + q * 8;
    const unsigned short* pb1 = pb0 + 16 * D_MODEL;
    const unsigned short* pA = anegT + c * D_MODEL + kbase + q * 8;
#pragma unroll
    for (int k0 = 0; k0 < 128; k0 += 32) {
        bf16x8 a0 = *reinterpret_cast<const bf16x8*>(pa0 + k0);
        bf16x8 a1 = *reinterpret_cast<const bf16x8*>(pa1 + k0);
        bf16x8 t0 = *reinterpret_cast<const bf16x8*>(pt0 + k0);
        bf16x8 t1 = *reinterpret_cast<const bf16x8*>(pt1 + k0);
        bf16x8 b0 = *reinterpret_cast<const bf16x8*>(pb0 + k0);
        bf16x8 b1 = *reinterpret_cast<const bf16x8*>(pb1 + k0);
        bf16x8 bA = *reinterpret_cast<const bf16x8*>(pA + k0);
        bf16x8 g0, g1;
#pragma unroll
        for (int e = 0; e < 8; e++) {
            g0[e] = (__bf16)((float)t0[e] * (float)a0[e]);
            g1[e] = (__bf16)((float)t1[e] * (float)a1[e]);
        }
        accb[0][0] = __builtin_amdgcn_mfma_f32_16x16x32_bf16(b0, a0, accb[0][0], 0, 0, 0);
        accb[0][1] = __builtin_amdgcn_mfma_f32_16x16x32_bf16(b1, a0, accb[0][1], 0, 0, 0);
        accb[1][0] = __builtin_amdgcn_mfma_f32_16x16x32_bf16(b0, a1, accb[1][0], 0, 0, 0);
        accb[1][1] = __builtin_amdgcn_mfma_f32_16x16x32_bf16(b1, a1, accb[1][1], 0, 0, 0);
        accw[0] = __builtin_amdgcn_mfma_f32_16x16x32_bf16(bA, g0, accw[0], 0, 0, 0);
        accw[1] = __builtin_amdgcn_mfma_f32_16x16x32_bf16(bA, g1, accw[1], 0, 0, 0);
    }
#pragma unroll
    for (int i = 0; i < 2; i++) {
        int row = mw + i * 16 + c;
#pragma unroll
        for (int j = 0; j < 2; j++)
            *reinterpret_cast<f32x4*>(&bcp[(ks * M_TOTAL + row) * 32 + j * 16 + q * 4]) = accb[i][j];
        *reinterpret_cast<f32x4*>(&wpp[(ks * M_TOTAL + row) * 16 + q * 4]) = accw[i];
    }
}

// ---------- scan phase 1: chunk-local scan -> h_loc, dtsum (inline k-split reduce) ----------
__global__ void __launch_bounds__(256) k_scan1(const unsigned short* __restrict__ dtb,
                                               const float* __restrict__ bcp,
                                               const float* __restrict__ wpp,
                                               const float* __restrict__ aneg,
                                               float* __restrict__ h_loc,
                                               float* __restrict__ dtsum) {
    __shared__ unsigned short s_dt[16][256];
    __shared__ float s_w[16][16];
    int dc = blockIdx.x & 3;
    int c = (blockIdx.x >> 2) & (CHUNKS - 1);
    int b = blockIdx.x >> 8;
    int tid = threadIdx.x;
    int d = dc * 256 + tid;
    float Ad[16];
    const float4* ar = reinterpret_cast<const float4*>(aneg + d * 16);
#pragma unroll
    for (int j = 0; j < 4; j++) {
        float4 a4 = ar[j];
        Ad[4 * j + 0] = a4.x; Ad[4 * j + 1] = a4.y;
        Ad[4 * j + 2] = a4.z; Ad[4 * j + 3] = a4.w;
    }
    float h[16];
#pragma unroll
    for (int n = 0; n < 16; n++) h[n] = 0.f;
    float dts = 0.f;

    int r8 = tid >> 5, col8 = (tid & 31) * 8;
    for (int t0 = 0; t0 < CLEN; t0 += 16) {
        __syncthreads();
        int rowbase = b * SEQ + c * CLEN + t0;
        *reinterpret_cast<uint4*>(&s_dt[r8][col8]) =
            *reinterpret_cast<const uint4*>(dtb + (rowbase + r8) * D_MODEL + dc * 256 + col8);
        *reinterpret_cast<uint4*>(&s_dt[8 + r8][col8]) =
            *reinterpret_cast<const uint4*>(dtb + (rowbase + 8 + r8) * D_MODEL + dc * 256 + col8);
        {
            int r = tid >> 4, n = tid & 15;
            int row = rowbase + r;
            float sB = 0.f, sw = 0.f;
#pragma unroll
            for (int ks = 0; ks < 8; ks++) {
                sB += bcp[(ks * M_TOTAL + row) * 32 + n];
                sw += wpp[(ks * M_TOTAL + row) * 16 + n];
            }
            s_w[r][n] = sB * sw;
        }
        __syncthreads();
        for (int r = 0; r < 16; r++) {
            float dtv = bf2f(s_dt[r][tid]);
            dts += dtv;
#pragma unroll
            for (int n = 0; n < 16; n++) {
                float ba = fexp2(dtv * Ad[n]);  // Ad pre-scaled by log2e
                h[n] = fmaf(ba, h[n], s_w[r][n]);
            }
        }
    }
    int base = ((b * CHUNKS + c) * D_MODEL + d) * 16;
#pragma unroll
    for (int j = 0; j < 4; j++) {
        f32x4 v = {h[4 * j], h[4 * j + 1], h[4 * j + 2], h[4 * j + 3]};
        *reinterpret_cast<f32x4*>(h_loc + base + 4 * j) = v;
    }
    dtsum[(b * CHUNKS + c) * D_MODEL + d] = dts;
}

// ---------- scan phase 2: combine chunks, 8-deep prefetch, 256 blocks x 128 thr ----------
__global__ void __launch_bounds__(128) k_scan2(float* __restrict__ h_inout,
                                               const float* __restrict__ dtsum,
                                               const float* __restrict__ aneg) {
    int idx = blockIdx.x * 128 + threadIdx.x;  // 32768
    int n = idx & 15;
    int d = (idx >> 4) & (D_MODEL - 1);
    int b = idx >> 14;
    float A = aneg[d * 16 + n];  // pre-scaled by log2e
    float H = 0.f;
    int off0 = b * CHUNKS * D_MODEL + d;
#pragma unroll 1
    for (int g = 0; g < CHUNKS; g += 8) {
        float hl[8], ds[8];
#pragma unroll
        for (int j = 0; j < 8; j++) {
            int off = off0 + (g + j) * D_MODEL;
            hl[j] = h_inout[off * 16 + n];
            ds[j] = dtsum[off];
        }
#pragma unroll
        for (int j = 0; j < 8; j++) {
            int off = off0 + (g + j) * D_MODEL;
            float P = fexp2(ds[j] * A);
            h_inout[off * 16 + n] = H;
            H = fmaf(P, H, hl[j]);
        }
    }
}

// ---------- scan phase 3: chunk scan from H_in; emit y (inline k-split reduce) ----------
__global__ void __launch_bounds__(256) k_scan3(const unsigned short* __restrict__ dtb,
                                               const unsigned short* __restrict__ xinb,
                                               const float* __restrict__ bcp,
                                               const float* __restrict__ wpp,
                                               const float* __restrict__ aneg,
                                               const float* __restrict__ dp,
                                               const float* __restrict__ H_in,
                                               float* __restrict__ out) {
    __shared__ unsigned short s_dt[16][256], s_u[16][256];
    __shared__ float s_w[16][16], s_c[16][16];
    int dc = blockIdx.x & 3;
    int c = (blockIdx.x >> 2) & (CHUNKS - 1);
    int b = blockIdx.x >> 8;
    int tid = threadIdx.x;
    int d = dc * 256 + tid;
    float Ad[16];
    const float4* ar = reinterpret_cast<const float4*>(aneg + d * 16);
#pragma unroll
    for (int j = 0; j < 4; j++) {
        float4 a4 = ar[j];
        Ad[4 * j + 0] = a4.x; Ad[4 * j + 1] = a4.y;
        Ad[4 * j + 2] = a4.z; Ad[4 * j + 3] = a4.w;
    }
    float Dpd = dp[d];
    float h[16];
    int base = ((b * CHUNKS + c) * D_MODEL + d) * 16;
#pragma unroll
    for (int j = 0; j < 4; j++) {
        f32x4 v = *reinterpret_cast<const f32x4*>(H_in + base + 4 * j);
        h[4 * j] = v[0]; h[4 * j + 1] = v[1]; h[4 * j + 2] = v[2]; h[4 * j + 3] = v[3];
    }

    int r8 = tid >> 5, col8 = (tid & 31) * 8;
    for (int t0 = 0; t0 < CLEN; t0 += 16) {
        __syncthreads();
        int rowbase = b * SEQ + c * CLEN + t0;
        *reinterpret_cast<uint4*>(&s_dt[r8][col8]) =
            *reinterpret_cast<const uint4*>(dtb + (rowbase + r8) * D_MODEL + dc * 256 + col8);
        *reinterpret_cast<uint4*>(&s_dt[8 + r8][col8]) =
            *reinterpret_cast<const uint4*>(dtb + (rowbase + 8 + r8) * D_MODEL + dc * 256 + col8);
        *reinterpret_cast<uint4*>(&s_u[r8][col8]) =
            *reinterpret_cast<const uint4*>(xinb + (rowbase + r8) * D_MODEL + dc * 256 + col8);
        *reinterpret_cast<uint4*>(&s_u[8 + r8][col8]) =
            *reinterpret_cast<const uint4*>(xinb + (rowbase + 8 + r8) * D_MODEL + dc * 256 + col8);
        {
            int r = tid >> 4, n = tid & 15;
            int row = rowbase + r;
            float sB = 0.f, sw = 0.f, sC = 0.f;
#pragma unroll
            for (int ks = 0; ks < 8; ks++) {
                sB += bcp[(ks * M_TOTAL + row) * 32 + n];
                sC += bcp[(ks * M_TOTAL + row) * 32 + 16 + n];
                sw += wpp[(ks * M_TOTAL + row) * 16 + n];
            }
            s_w[r][n] = sB * sw;
            s_c[r][n] = sC;
        }
        __syncthreads();
        for (int r = 0; r < 16; r++) {
            float dtv = bf2f(s_dt[r][tid]), uv = bf2f(s_u[r][tid]);
            float y = Dpd * uv;
#pragma unroll
            for (int n = 0; n < 16; n++) {
                float ba = fexp2(dtv * Ad[n]);  // Ad pre-scaled by log2e
                h[n] = fmaf(ba, h[n], s_w[r][n]);
                y = fmaf(h[n], s_c[r][n], y);
            }
            out[(rowbase + r) * D_MODEL + d] = y;
        }
    }
}

extern "C" void kernel_launch(void* const* d_in, const int* in_sizes, int n_in,
                              void* d_out, int out_size, void* d_ws, size_t ws_size,
                              hipStream_t stream) {
    const float* x     = (const float*)d_in[0];
    const float* w_in  = (const float*)d_in[1];
    const float* w_x   = (const float*)d_in[2];
    const float* w_dt  = (const float*)d_in[3];
    const float* b_dt  = (const float*)d_in[4];
    const float* A_log = (const float*)d_in[5];
    const float* Dp    = (const float*)d_in[6];
    float* out = (float*)d_out;

    char* ws = (char*)d_ws;
    // footprint capped below proven-safe 39124992 B
    unsigned short* xb   = (unsigned short*)(ws + 0);          // 8 MB  (dead after gemm_xin)
    unsigned short* bt   = (unsigned short*)(ws + 8388608);    // 2 MB  w_in^T (dead after gemm_xin)
    unsigned short* xinb = (unsigned short*)(ws + 10485760);   // 8 MB
    unsigned short* dtb  = (unsigned short*)(ws + 18874368);   // 8 MB
    float* bcp           = (float*)(ws + 27262976);            // 4 MB  -> ends 31457280
    float* wpp           = (float*)(ws + 31457280);            // 2 MB  -> ends 33554432
    unsigned short* wxT  = (unsigned short*)(ws + 35651584);   // 128 KB
    unsigned short* wxBC = (unsigned short*)(ws + 35782656);   // 64 KB
    unsigned short* wdtT = (unsigned short*)(ws + 35848192);   // 128 KB
    float* aneg          = (float*)(ws + 35979264);            // 64 KB (pre-scaled by log2e)
    unsigned short* anegT= (unsigned short*)(ws + 36044800);   // 32 KB -> ends 36077568
    // scan-phase overlays of dead xb/bt regions:
    float* h_loc         = (float*)(ws + 0);                   // 8 MB  [b][c][d][n]
    float* dtsum         = (float*)(ws + 8388608);             // 512 KB [b][c][d]

    k_setup<<<5824, 256, 0, stream>>>(x, w_in, w_x, w_dt, A_log, xb, bt, wxT, wxBC, wdtT, aneg, anegT);
    k_gemm_xin<<<512, 256, 0, stream>>>(xb, bt, xinb);
    k_dt<<<64, 256, 0, stream>>>(xinb, wxT, wdtT, b_dt, dtb);
    k_bcw<<<256, 256, 0, stream>>>(xinb, dtb, wxBC, anegT, bcp, wpp);
    k_scan1<<<BATCH * CHUNKS * 4, 256, 0, stream>>>(dtb, bcp, wpp, aneg, h_loc, dtsum);
    k_scan2<<<256, 128, 0, stream>>>(h_loc, dtsum, aneg);
    k_scan3<<<BATCH * CHUNKS * 4, 256, 0, stream>>>(dtb, xinb, bcp, wpp, aneg, Dp, h_loc, out);
}

// Round 7
// 166.701 us; speedup vs baseline: 1.6542x; 1.2239x over previous
//
#include <hip/hip_runtime.h>
#include <hip/hip_bf16.h>

#define D_MODEL 1024
#define D_STATE 16
#define DT_RANK 64
#define SEQ 2048
#define BATCH 2
#define M_TOTAL 4096
#define CHUNKS 64
#define CLEN 32
#define LOG2E 1.44269504088896f

typedef __bf16 bf16x8 __attribute__((ext_vector_type(8)));
typedef float f32x4 __attribute__((ext_vector_type(4)));

__device__ __forceinline__ unsigned short f2bf(float f) {
    union { float f; unsigned int u; } v; v.f = f;
    unsigned int r = v.u + 0x7FFFu + ((v.u >> 16) & 1u);
    return (unsigned short)(r >> 16);
}
__device__ __forceinline__ float bf2f(unsigned short u) {
    union { unsigned int i; float f; } v; v.i = ((unsigned int)u) << 16; return v.f;
}
__device__ __forceinline__ void gload16(const void* g, void* l) {
    __builtin_amdgcn_global_load_lds(
        (const __attribute__((address_space(1))) unsigned int*)g,
        (__attribute__((address_space(3))) unsigned int*)l, 16, 0, 0);
}
__device__ __forceinline__ float fexp2(float x) { return __builtin_amdgcn_exp2f(x); }

// ---------- fused setup ----------
__global__ void __launch_bounds__(256) k_setup(const float* __restrict__ x,
                                               const float* __restrict__ win,
                                               const float* __restrict__ wx,
                                               const float* __restrict__ wdt,
                                               const float* __restrict__ alog,
                                               unsigned short* __restrict__ xb,
                                               unsigned short* __restrict__ bt,
                                               unsigned short* __restrict__ wxT,
                                               unsigned short* __restrict__ wxBC,
                                               unsigned short* __restrict__ wdtT,
                                               float* __restrict__ aneg,
                                               unsigned short* __restrict__ anegT) {
    __shared__ float tile[32][33];
    int blk = blockIdx.x;
    int t = threadIdx.x;
    if (blk < 4096) {  // x -> bf16
        int i = blk * 256 + t;
        float4 v = reinterpret_cast<const float4*>(x)[i];
        ushort4 o;
        o.x = f2bf(v.x); o.y = f2bf(v.y); o.z = f2bf(v.z); o.w = f2bf(v.w);
        reinterpret_cast<ushort4*>(xb)[i] = o;
    } else if (blk < 5120) {  // w_in^T -> bt
        int blk2 = blk - 4096;
        int bx = blk2 & 31, by = blk2 >> 5;
        int tx = t & 31, ty = t >> 5;
        int xc = bx * 32 + tx;
#pragma unroll
        for (int j = 0; j < 4; j++)
            tile[ty + 8 * j][tx] = win[(by * 32 + ty + 8 * j) * D_MODEL + xc];
        __syncthreads();
        int x2 = by * 32 + tx;
#pragma unroll
        for (int j = 0; j < 4; j++)
            bt[(bx * 32 + ty + 8 * j) * D_MODEL + x2] = f2bf(tile[tx][ty + 8 * j]);
    } else if (blk < 5376) {  // wxT[p][e] = w_x[e][p], p<64
        int idx = (blk - 5120) * 256 + t;
        int e = idx & 1023, p = idx >> 10;
        wxT[p * D_MODEL + e] = f2bf(wx[e * 96 + p]);
    } else if (blk < 5504) {  // wxBC[p][e] = w_x[e][64+p], p<32
        int idx = (blk - 5376) * 256 + t;
        int e = idx & 1023, p = idx >> 10;
        wxBC[p * D_MODEL + e] = f2bf(wx[e * 96 + 64 + p]);
    } else if (blk < 5568) {  // aneg (fp32, [d][n], pre-scaled by log2e) + anegT (bf16, [n][d], UNscaled)
        int i = (blk - 5504) * 256 + t;  // 64 blocks -> 16384 exact
        float v = -expf(alog[i]);
        aneg[i] = v * LOG2E;
        anegT[(i & 15) * D_MODEL + (i >> 4)] = f2bf(v);
    } else {  // wdtT[d][k] = w_dt[k][d] bf16  (256 blocks -> 65536)
        int idx = (blk - 5568) * 256 + t;
        int d = idx & 1023, k = idx >> 10;
        wdtT[d * DT_RANK + k] = f2bf(wdt[k * D_MODEL + d]);
    }
}

// ---------- x_in GEMM: x_in = x @ w_in. 64x128 tile, BK=64, dbuf, XOR-swizzle, grid 512 ----------
__global__ void __launch_bounds__(256) k_gemm_xin(const unsigned short* __restrict__ xb,
                                                  const unsigned short* __restrict__ bt,
                                                  unsigned short* __restrict__ xinb) {
    __shared__ unsigned short sA[2][64 * 64];
    __shared__ unsigned short sB[2][128 * 64];
    int bid = blockIdx.x;        // 512 = 64 m-tiles x 8 n-tiles
    int m0 = (bid & 63) * 64;
    int n0 = (bid >> 6) * 128;
    int t = threadIdx.x;
    int lane = t & 63;
    int w = t >> 6;
    int wm = (w >> 1) * 32, wn = (w & 1) * 64;
    int c = lane & 15, q = lane >> 4;

    const unsigned short* gA[2];
    const unsigned short* gB[4];
#pragma unroll
    for (int L = 0; L < 2; L++) {
        int s = L * 256 + t;
        int row = s >> 3, ch = (s & 7) ^ (row & 7);
        gA[L] = xb + (m0 + row) * D_MODEL + ch * 8;
    }
#pragma unroll
    for (int L = 0; L < 4; L++) {
        int s = L * 256 + t;
        int row = s >> 3, ch = (s & 7) ^ (row & 7);
        gB[L] = bt + (n0 + row) * D_MODEL + ch * 8;
    }

    f32x4 acc[2][4] = {};
    {
        char* la = (char*)&sA[0][0] + w * 1024;
        char* lb = (char*)&sB[0][0] + w * 1024;
#pragma unroll
        for (int L = 0; L < 2; L++) gload16(gA[L], la + L * 4096);
#pragma unroll
        for (int L = 0; L < 4; L++) gload16(gB[L], lb + L * 4096);
    }
    int cur = 0;
    for (int it = 0; it < 16; it++) {
        __syncthreads();
        if (it + 1 < 16) {
            int kn = (it + 1) * 64;
            char* la = (char*)&sA[cur ^ 1][0] + w * 1024;
            char* lb = (char*)&sB[cur ^ 1][0] + w * 1024;
#pragma unroll
            for (int L = 0; L < 2; L++) gload16(gA[L] + kn, la + L * 4096);
#pragma unroll
            for (int L = 0; L < 4; L++) gload16(gB[L] + kn, lb + L * 4096);
        }
#pragma unroll
        for (int kk = 0; kk < 2; kk++) {
            int perm = (((kk << 2) | q) ^ (c & 7)) << 3;
            bf16x8 af[2], bfr[4];
#pragma unroll
            for (int i = 0; i < 2; i++)
                af[i] = *reinterpret_cast<const bf16x8*>(&sA[cur][(wm + i * 16 + c) * 64 + perm]);
#pragma unroll
            for (int j = 0; j < 4; j++)
                bfr[j] = *reinterpret_cast<const bf16x8*>(&sB[cur][(wn + j * 16 + c) * 64 + perm]);
            // swapped operands: lane owns 4 consecutive n-cols
#pragma unroll
            for (int i = 0; i < 2; i++)
#pragma unroll
                for (int j = 0; j < 4; j++)
                    acc[i][j] = __builtin_amdgcn_mfma_f32_16x16x32_bf16(bfr[j], af[i], acc[i][j], 0, 0, 0);
        }
        cur ^= 1;
    }
#pragma unroll
    for (int i = 0; i < 2; i++) {
        int row = m0 + wm + i * 16 + c;
#pragma unroll
        for (int j = 0; j < 4; j++) {
            int col = n0 + wn + j * 16 + q * 4;
            ushort4 o;
            o.x = f2bf(acc[i][j][0]); o.y = f2bf(acc[i][j][1]);
            o.z = f2bf(acc[i][j][2]); o.w = f2bf(acc[i][j][3]);
            *reinterpret_cast<ushort4*>(&xinb[row * D_MODEL + col]) = o;
        }
    }
}

// ---------- x_low partials: xlp[ks] = x_in[:, ks*128:+128] @ wxT[:, ks*128:+128]^T (256 blk) ----------
__global__ void __launch_bounds__(256) k_xlowp(const unsigned short* __restrict__ xinb,
                                               const unsigned short* __restrict__ wxT,
                                               float* __restrict__ xlp) {
    int bid = blockIdx.x;  // 256 = 32 mtiles x 8 ksplit
    int m0 = (bid & 31) * 128;
    int ks = bid >> 5;
    int kbase = ks * 128;
    int t = threadIdx.x;
    int lane = t & 63, w = t >> 6;
    int c = lane & 15, q = lane >> 4;
    int mw = m0 + w * 32;
    f32x4 acc[2][4] = {};
    const unsigned short* pa0 = xinb + (mw + c) * D_MODEL + kbase + q * 8;
    const unsigned short* pa1 = pa0 + 16 * D_MODEL;
    const unsigned short* pw = wxT + c * D_MODEL + kbase + q * 8;
#pragma unroll
    for (int k0 = 0; k0 < 128; k0 += 32) {
        bf16x8 a0 = *reinterpret_cast<const bf16x8*>(pa0 + k0);
        bf16x8 a1 = *reinterpret_cast<const bf16x8*>(pa1 + k0);
#pragma unroll
        for (int j = 0; j < 4; j++) {
            bf16x8 wf = *reinterpret_cast<const bf16x8*>(pw + j * 16 * D_MODEL + k0);
            acc[0][j] = __builtin_amdgcn_mfma_f32_16x16x32_bf16(wf, a0, acc[0][j], 0, 0, 0);
            acc[1][j] = __builtin_amdgcn_mfma_f32_16x16x32_bf16(wf, a1, acc[1][j], 0, 0, 0);
        }
    }
    // swapped C/D: lane col(c) = m-row, rows q*4+r = p -> float4 stores
#pragma unroll
    for (int i = 0; i < 2; i++) {
        int row = mw + i * 16 + c;
#pragma unroll
        for (int j = 0; j < 4; j++)
            *reinterpret_cast<f32x4*>(&xlp[(ks * M_TOTAL + row) * DT_RANK + j * 16 + q * 4]) = acc[i][j];
    }
}

// ---------- x_low reduce: xlow[m][p] = bf16(sum_ks xlp), coalesced, 256 blocks ----------
__global__ void __launch_bounds__(256) k_xred(const float* __restrict__ xlp,
                                              unsigned short* __restrict__ xlow) {
    int i = blockIdx.x * 256 + threadIdx.x;  // 65536 vec4-groups
    int row = i >> 4;
    int off = (i & 15) * 4;
    f32x4 s = {};
#pragma unroll
    for (int ks = 0; ks < 8; ks++)
        s += *reinterpret_cast<const f32x4*>(&xlp[(ks * M_TOTAL + row) * DT_RANK + off]);
    ushort4 o;
    o.x = f2bf(s[0]); o.y = f2bf(s[1]); o.z = f2bf(s[2]); o.w = f2bf(s[3]);
    *reinterpret_cast<ushort4*>(&xlow[row * DT_RANK + off]) = o;
}

// ---------- dt GEMM: dt = softplus(x_low @ w_dt + b_dt) scaled; K=64, bf16 A staged via gload16 ----------
__global__ void __launch_bounds__(256) k_gemm_dt(const unsigned short* __restrict__ xlow,
                                                 const unsigned short* __restrict__ wdtT,
                                                 const float* __restrict__ bdt,
                                                 unsigned short* __restrict__ dtb) {
    __shared__ unsigned short sA[128 * 64];
    int bid = blockIdx.x;  // 256 = 32 m x 8 n
    int m0 = (bid & 31) * 128;
    int n0 = (bid >> 5) * 128;
    int t = threadIdx.x;
    int lane = t & 63, w = t >> 6;
    int c = lane & 15, q = lane >> 4;

    // stage A tile (128 rows x 64 k bf16) with pre-swizzled SOURCE, linear LDS dest
    {
        char* la = (char*)&sA[0] + w * 1024;
#pragma unroll
        for (int L = 0; L < 4; L++) {
            int s = L * 256 + t;
            int row = s >> 3, ch = (s & 7) ^ (row & 7);
            gload16(xlow + (m0 + row) * DT_RANK + ch * 8, la + L * 4096);
        }
    }
    __syncthreads();

    int mw = m0 + w * 32;
    f32x4 acc[2][8] = {};
#pragma unroll
    for (int kk = 0; kk < 2; kk++) {
        bf16x8 af[2];
#pragma unroll
        for (int i = 0; i < 2; i++)
            af[i] = *reinterpret_cast<const bf16x8*>(
                &sA[(w * 32 + i * 16 + c) * 64 + ((((kk << 2) | q)) ^ (c & 7)) * 8]);
#pragma unroll
        for (int j = 0; j < 8; j++) {
            bf16x8 bfr = *reinterpret_cast<const bf16x8*>(
                &wdtT[(n0 + j * 16 + c) * DT_RANK + kk * 32 + q * 8]);
            acc[0][j] = __builtin_amdgcn_mfma_f32_16x16x32_bf16(bfr, af[0], acc[0][j], 0, 0, 0);
            acc[1][j] = __builtin_amdgcn_mfma_f32_16x16x32_bf16(bfr, af[1], acc[1][j], 0, 0, 0);
        }
    }
    // epilogue: softplus -> dtb (swapped C/D: lane owns 4 consecutive d)
#pragma unroll
    for (int i = 0; i < 2; i++) {
        int row = mw + i * 16 + c;
#pragma unroll
        for (int j = 0; j < 8; j++) {
            int dcol = n0 + j * 16 + q * 4;
            float4 bv = *reinterpret_cast<const float4*>(&bdt[dcol]);
            ushort4 o;
            {
                float xv = acc[i][j][0] + bv.x;
                float sp = fmaxf(xv, 0.f) + __logf(1.f + __expf(-fabsf(xv)));
                o.x = f2bf(sp * 0.099f + 0.001f);
            }
            {
                float xv = acc[i][j][1] + bv.y;
                float sp = fmaxf(xv, 0.f) + __logf(1.f + __expf(-fabsf(xv)));
                o.y = f2bf(sp * 0.099f + 0.001f);
            }
            {
                float xv = acc[i][j][2] + bv.z;
                float sp = fmaxf(xv, 0.f) + __logf(1.f + __expf(-fabsf(xv)));
                o.z = f2bf(sp * 0.099f + 0.001f);
            }
            {
                float xv = acc[i][j][3] + bv.w;
                float sp = fmaxf(xv, 0.f) + __logf(1.f + __expf(-fabsf(xv)));
                o.w = f2bf(sp * 0.099f + 0.001f);
            }
            *reinterpret_cast<ushort4*>(&dtb[row * D_MODEL + dcol]) = o;
        }
    }
}

// ---------- BCW GEMM: bcp = x_in @ wxBC^T ; wpp = (dt*u) @ anegT^T ; ksplit=8, grid 256 ----------
__global__ void __launch_bounds__(256) k_bcw(const unsigned short* __restrict__ xinb,
                                             const unsigned short* __restrict__ dtb,
                                             const unsigned short* __restrict__ wxBC,
                                             const unsigned short* __restrict__ anegT,
                                             float* __restrict__ bcp,
                                             float* __restrict__ wpp) {
    int bid = blockIdx.x;  // 256 = 32 mtiles x 8 ksplit
    int m0 = (bid & 31) * 128;
    int ks = bid >> 5;
    int kbase = ks * 128;
    int t = threadIdx.x;
    int lane = t & 63, w = t >> 6;
    int c = lane & 15, q = lane >> 4;
    int mw = m0 + w * 32;
    f32x4 accb[2][2] = {};
    f32x4 accw[2] = {};
    const unsigned short* pa0 = xinb + (mw + c) * D_MODEL + kbase + q * 8;
    const unsigned short* pa1 = pa0 + 16 * D_MODEL;
    const unsigned short* pt0 = dtb + (mw + c) * D_MODEL + kbase + q * 8;
    const unsigned short* pt1 = pt0 + 16 * D_MODEL;
    const unsigned short* pb0 = wxBC + c * D_MODEL + kbase + q * 8;
    const unsigned short* pb1 = pb0 + 16 * D_MODEL;
    const unsigned short* pA = anegT + c * D_MODEL + kbase + q * 8;
#pragma unroll
    for (int k0 = 0; k0 < 128; k0 += 32) {
        bf16x8 a0 = *reinterpret_cast<const bf16x8*>(pa0 + k0);
        bf16x8 a1 = *reinterpret_cast<const bf16x8*>(pa1 + k0);
        bf16x8 t0 = *reinterpret_cast<const bf16x8*>(pt0 + k0);
        bf16x8 t1 = *reinterpret_cast<const bf16x8*>(pt1 + k0);
        bf16x8 b0 = *reinterpret_cast<const bf16x8*>(pb0 + k0);
        bf16x8 b1 = *reinterpret_cast<const bf16x8*>(pb1 + k0);
        bf16x8 bA = *reinterpret_cast<const bf16x8*>(pA + k0);
        bf16x8 g0, g1;
#pragma unroll
        for (int e = 0; e < 8; e++) {
            g0[e] = (__bf16)((float)t0[e] * (float)a0[e]);
            g1[e] = (__bf16)((float)t1[e] * (float)a1[e]);
        }
        accb[0][0] = __builtin_amdgcn_mfma_f32_16x16x32_bf16(b0, a0, accb[0][0], 0, 0, 0);
        accb[0][1] = __builtin_amdgcn_mfma_f32_16x16x32_bf16(b1, a0, accb[0][1], 0, 0, 0);
        accb[1][0] = __builtin_amdgcn_mfma_f32_16x16x32_bf16(b0, a1, accb[1][0], 0, 0, 0);
        accb[1][1] = __builtin_amdgcn_mfma_f32_16x16x32_bf16(b1, a1, accb[1][1], 0, 0, 0);
        accw[0] = __builtin_amdgcn_mfma_f32_16x16x32_bf16(bA, g0, accw[0], 0, 0, 0);
        accw[1] = __builtin_amdgcn_mfma_f32_16x16x32_bf16(bA, g1, accw[1], 0, 0, 0);
    }
#pragma unroll
    for (int i = 0; i < 2; i++) {
        int row = mw + i * 16 + c;
#pragma unroll
        for (int j = 0; j < 2; j++)
            *reinterpret_cast<f32x4*>(&bcp[(ks * M_TOTAL + row) * 32 + j * 16 + q * 4]) = accb[i][j];
        *reinterpret_cast<f32x4*>(&wpp[(ks * M_TOTAL + row) * 16 + q * 4]) = accw[i];
    }
}

// ---------- scan phase 1: chunk-local scan -> h_loc, dtsum (inline k-split reduce) ----------
__global__ void __launch_bounds__(256) k_scan1(const unsigned short* __restrict__ dtb,
                                               const float* __restrict__ bcp,
                                               const float* __restrict__ wpp,
                                               const float* __restrict__ aneg,
                                               float* __restrict__ h_loc,
                                               float* __restrict__ dtsum) {
    __shared__ unsigned short s_dt[16][256];
    __shared__ float s_w[16][16];
    int dc = blockIdx.x & 3;
    int c = (blockIdx.x >> 2) & (CHUNKS - 1);
    int b = blockIdx.x >> 8;
    int tid = threadIdx.x;
    int d = dc * 256 + tid;
    float Ad[16];
    const float4* ar = reinterpret_cast<const float4*>(aneg + d * 16);
#pragma unroll
    for (int j = 0; j < 4; j++) {
        float4 a4 = ar[j];
        Ad[4 * j + 0] = a4.x; Ad[4 * j + 1] = a4.y;
        Ad[4 * j + 2] = a4.z; Ad[4 * j + 3] = a4.w;
    }
    float h[16];
#pragma unroll
    for (int n = 0; n < 16; n++) h[n] = 0.f;
    float dts = 0.f;

    int r8 = tid >> 5, col8 = (tid & 31) * 8;
    for (int t0 = 0; t0 < CLEN; t0 += 16) {
        __syncthreads();
        int rowbase = b * SEQ + c * CLEN + t0;
        *reinterpret_cast<uint4*>(&s_dt[r8][col8]) =
            *reinterpret_cast<const uint4*>(dtb + (rowbase + r8) * D_MODEL + dc * 256 + col8);
        *reinterpret_cast<uint4*>(&s_dt[8 + r8][col8]) =
            *reinterpret_cast<const uint4*>(dtb + (rowbase + 8 + r8) * D_MODEL + dc * 256 + col8);
        {
            int r = tid >> 4, n = tid & 15;
            int row = rowbase + r;
            float sB = 0.f, sw = 0.f;
#pragma unroll
            for (int ks = 0; ks < 8; ks++) {
                sB += bcp[(ks * M_TOTAL + row) * 32 + n];
                sw += wpp[(ks * M_TOTAL + row) * 16 + n];
            }
            s_w[r][n] = sB * sw;
        }
        __syncthreads();
        for (int r = 0; r < 16; r++) {
            float dtv = bf2f(s_dt[r][tid]);
            dts += dtv;
#pragma unroll
            for (int n = 0; n < 16; n++) {
                float ba = fexp2(dtv * Ad[n]);  // Ad pre-scaled by log2e
                h[n] = fmaf(ba, h[n], s_w[r][n]);
            }
        }
    }
    int base = ((b * CHUNKS + c) * D_MODEL + d) * 16;
#pragma unroll
    for (int j = 0; j < 4; j++) {
        f32x4 v = {h[4 * j], h[4 * j + 1], h[4 * j + 2], h[4 * j + 3]};
        *reinterpret_cast<f32x4*>(h_loc + base + 4 * j) = v;
    }
    dtsum[(b * CHUNKS + c) * D_MODEL + d] = dts;
}

// ---------- scan phase 2: combine chunks, 8-deep prefetch, 256 blocks x 128 thr ----------
__global__ void __launch_bounds__(128) k_scan2(float* __restrict__ h_inout,
                                               const float* __restrict__ dtsum,
                                               const float* __restrict__ aneg) {
    int idx = blockIdx.x * 128 + threadIdx.x;  // 32768
    int n = idx & 15;
    int d = (idx >> 4) & (D_MODEL - 1);
    int b = idx >> 14;
    float A = aneg[d * 16 + n];  // pre-scaled by log2e
    float H = 0.f;
    int off0 = b * CHUNKS * D_MODEL + d;
#pragma unroll 1
    for (int g = 0; g < CHUNKS; g += 8) {
        float hl[8], ds[8];
#pragma unroll
        for (int j = 0; j < 8; j++) {
            int off = off0 + (g + j) * D_MODEL;
            hl[j] = h_inout[off * 16 + n];
            ds[j] = dtsum[off];
        }
#pragma unroll
        for (int j = 0; j < 8; j++) {
            int off = off0 + (g + j) * D_MODEL;
            float P = fexp2(ds[j] * A);
            h_inout[off * 16 + n] = H;
            H = fmaf(P, H, hl[j]);
        }
    }
}

// ---------- scan phase 3: chunk scan from H_in; emit y (inline k-split reduce) ----------
__global__ void __launch_bounds__(256) k_scan3(const unsigned short* __restrict__ dtb,
                                               const unsigned short* __restrict__ xinb,
                                               const float* __restrict__ bcp,
                                               const float* __restrict__ wpp,
                                               const float* __restrict__ aneg,
                                               const float* __restrict__ dp,
                                               const float* __restrict__ H_in,
                                               float* __restrict__ out) {
    __shared__ unsigned short s_dt[16][256], s_u[16][256];
    __shared__ float s_w[16][16], s_c[16][16];
    int dc = blockIdx.x & 3;
    int c = (blockIdx.x >> 2) & (CHUNKS - 1);
    int b = blockIdx.x >> 8;
    int tid = threadIdx.x;
    int d = dc * 256 + tid;
    float Ad[16];
    const float4* ar = reinterpret_cast<const float4*>(aneg + d * 16);
#pragma unroll
    for (int j = 0; j < 4; j++) {
        float4 a4 = ar[j];
        Ad[4 * j + 0] = a4.x; Ad[4 * j + 1] = a4.y;
        Ad[4 * j + 2] = a4.z; Ad[4 * j + 3] = a4.w;
    }
    float Dpd = dp[d];
    float h[16];
    int base = ((b * CHUNKS + c) * D_MODEL + d) * 16;
#pragma unroll
    for (int j = 0; j < 4; j++) {
        f32x4 v = *reinterpret_cast<const f32x4*>(H_in + base + 4 * j);
        h[4 * j] = v[0]; h[4 * j + 1] = v[1]; h[4 * j + 2] = v[2]; h[4 * j + 3] = v[3];
    }

    int r8 = tid >> 5, col8 = (tid & 31) * 8;
    for (int t0 = 0; t0 < CLEN; t0 += 16) {
        __syncthreads();
        int rowbase = b * SEQ + c * CLEN + t0;
        *reinterpret_cast<uint4*>(&s_dt[r8][col8]) =
            *reinterpret_cast<const uint4*>(dtb + (rowbase + r8) * D_MODEL + dc * 256 + col8);
        *reinterpret_cast<uint4*>(&s_dt[8 + r8][col8]) =
            *reinterpret_cast<const uint4*>(dtb + (rowbase + 8 + r8) * D_MODEL + dc * 256 + col8);
        *reinterpret_cast<uint4*>(&s_u[r8][col8]) =
            *reinterpret_cast<const uint4*>(xinb + (rowbase + r8) * D_MODEL + dc * 256 + col8);
        *reinterpret_cast<uint4*>(&s_u[8 + r8][col8]) =
            *reinterpret_cast<const uint4*>(xinb + (rowbase + 8 + r8) * D_MODEL + dc * 256 + col8);
        {
            int r = tid >> 4, n = tid & 15;
            int row = rowbase + r;
            float sB = 0.f, sw = 0.f, sC = 0.f;
#pragma unroll
            for (int ks = 0; ks < 8; ks++) {
                sB += bcp[(ks * M_TOTAL + row) * 32 + n];
                sC += bcp[(ks * M_TOTAL + row) * 32 + 16 + n];
                sw += wpp[(ks * M_TOTAL + row) * 16 + n];
            }
            s_w[r][n] = sB * sw;
            s_c[r][n] = sC;
        }
        __syncthreads();
        for (int r = 0; r < 16; r++) {
            float dtv = bf2f(s_dt[r][tid]), uv = bf2f(s_u[r][tid]);
            float y = Dpd * uv;
#pragma unroll
            for (int n = 0; n < 16; n++) {
                float ba = fexp2(dtv * Ad[n]);  // Ad pre-scaled by log2e
                h[n] = fmaf(ba, h[n], s_w[r][n]);
                y = fmaf(h[n], s_c[r][n], y);
            }
            out[(rowbase + r) * D_MODEL + d] = y;
        }
    }
}

extern "C" void kernel_launch(void* const* d_in, const int* in_sizes, int n_in,
                              void* d_out, int out_size, void* d_ws, size_t ws_size,
                              hipStream_t stream) {
    const float* x     = (const float*)d_in[0];
    const float* w_in  = (const float*)d_in[1];
    const float* w_x   = (const float*)d_in[2];
    const float* w_dt  = (const float*)d_in[3];
    const float* b_dt  = (const float*)d_in[4];
    const float* A_log = (const float*)d_in[5];
    const float* Dp    = (const float*)d_in[6];
    float* out = (float*)d_out;

    char* ws = (char*)d_ws;
    // footprint capped below proven-safe 39124992 B
    unsigned short* xb   = (unsigned short*)(ws + 0);          // 8 MB  (dead after gemm_xin)
    unsigned short* bt   = (unsigned short*)(ws + 8388608);    // 2 MB  w_in^T (dead after gemm_xin)
    unsigned short* xinb = (unsigned short*)(ws + 10485760);   // 8 MB
    unsigned short* dtb  = (unsigned short*)(ws + 18874368);   // 8 MB
    float* xlp           = (float*)(ws + 27262976);            // 8 MB f32 partials -> ends 35651584 (dead after xred)
    // overlays of the xlp region (written by k_bcw, which runs after xred/gemm_dt):
    float* bcp           = (float*)(ws + 27262976);            // 4 MB  -> ends 31457280
    float* wpp           = (float*)(ws + 31457280);            // 2 MB  -> ends 33554432
    // weight buffers PAST the xlp shadow:
    unsigned short* wxT  = (unsigned short*)(ws + 35651584);   // 128 KB
    unsigned short* wxBC = (unsigned short*)(ws + 35782656);   // 64 KB
    unsigned short* wdtT = (unsigned short*)(ws + 35848192);   // 128 KB
    float* aneg          = (float*)(ws + 35979264);            // 64 KB (pre-scaled by log2e)
    unsigned short* anegT= (unsigned short*)(ws + 36044800);   // 32 KB -> ends 36077568
    unsigned short* xlow = (unsigned short*)(ws + 36077568);   // 512 KB bf16 [4096][64] -> ends 36601856
    // scan-phase overlays of dead xb/bt regions:
    float* h_loc         = (float*)(ws + 0);                   // 8 MB  [b][c][d][n]
    float* dtsum         = (float*)(ws + 8388608);             // 512 KB [b][c][d]

    k_setup<<<5824, 256, 0, stream>>>(x, w_in, w_x, w_dt, A_log, xb, bt, wxT, wxBC, wdtT, aneg, anegT);
    k_gemm_xin<<<512, 256, 0, stream>>>(xb, bt, xinb);
    k_xlowp<<<256, 256, 0, stream>>>(xinb, wxT, xlp);
    k_xred<<<256, 256, 0, stream>>>(xlp, xlow);
    k_gemm_dt<<<256, 256, 0, stream>>>(xlow, wdtT, b_dt, dtb);
    k_bcw<<<256, 256, 0, stream>>>(xinb, dtb, wxBC, anegT, bcp, wpp);
    k_scan1<<<BATCH * CHUNKS * 4, 256, 0, stream>>>(dtb, bcp, wpp, aneg, h_loc, dtsum);
    k_scan2<<<256, 128, 0, stream>>>(h_loc, dtsum, aneg);
    k_scan3<<<BATCH * CHUNKS * 4, 256, 0, stream>>>(dtb, xinb, bcp, wpp, aneg, Dp, h_loc, out);
}

// Round 8
// 159.856 us; speedup vs baseline: 1.7250x; 1.0428x over previous
//
#include <hip/hip_runtime.h>
#include <hip/hip_bf16.h>

#define D_MODEL 1024
#define D_STATE 16
#define DT_RANK 64
#define SEQ 2048
#define BATCH 2
#define M_TOTAL 4096
#define CHUNKS 64
#define CLEN 32
#define LOG2E 1.44269504088896f

typedef __bf16 bf16x8 __attribute__((ext_vector_type(8)));
typedef float f32x4 __attribute__((ext_vector_type(4)));

__device__ __forceinline__ unsigned short f2bf(float f) {
    union { float f; unsigned int u; } v; v.f = f;
    unsigned int r = v.u + 0x7FFFu + ((v.u >> 16) & 1u);
    return (unsigned short)(r >> 16);
}
__device__ __forceinline__ float bf2f(unsigned short u) {
    union { unsigned int i; float f; } v; v.i = ((unsigned int)u) << 16; return v.f;
}
__device__ __forceinline__ void gload16(const void* g, void* l) {
    __builtin_amdgcn_global_load_lds(
        (const __attribute__((address_space(1))) unsigned int*)g,
        (__attribute__((address_space(3))) unsigned int*)l, 16, 0, 0);
}
__device__ __forceinline__ float fexp2(float x) { return __builtin_amdgcn_exp2f(x); }

// ---------- fused setup ----------
__global__ void __launch_bounds__(256) k_setup(const float* __restrict__ x,
                                               const float* __restrict__ win,
                                               const float* __restrict__ wx,
                                               const float* __restrict__ wdt,
                                               const float* __restrict__ alog,
                                               unsigned short* __restrict__ xb,
                                               unsigned short* __restrict__ bt,
                                               unsigned short* __restrict__ wxT,
                                               unsigned short* __restrict__ wxBC,
                                               unsigned short* __restrict__ wdtT,
                                               float* __restrict__ aneg,
                                               unsigned short* __restrict__ anegT) {
    __shared__ float tile[32][33];
    int blk = blockIdx.x;
    int t = threadIdx.x;
    if (blk < 4096) {  // x -> bf16
        int i = blk * 256 + t;
        float4 v = reinterpret_cast<const float4*>(x)[i];
        ushort4 o;
        o.x = f2bf(v.x); o.y = f2bf(v.y); o.z = f2bf(v.z); o.w = f2bf(v.w);
        reinterpret_cast<ushort4*>(xb)[i] = o;
    } else if (blk < 5120) {  // w_in^T -> bt
        int blk2 = blk - 4096;
        int bx = blk2 & 31, by = blk2 >> 5;
        int tx = t & 31, ty = t >> 5;
        int xc = bx * 32 + tx;
#pragma unroll
        for (int j = 0; j < 4; j++)
            tile[ty + 8 * j][tx] = win[(by * 32 + ty + 8 * j) * D_MODEL + xc];
        __syncthreads();
        int x2 = by * 32 + tx;
#pragma unroll
        for (int j = 0; j < 4; j++)
            bt[(bx * 32 + ty + 8 * j) * D_MODEL + x2] = f2bf(tile[tx][ty + 8 * j]);
    } else if (blk < 5376) {  // wxT[p][e] = w_x[e][p], p<64
        int idx = (blk - 5120) * 256 + t;
        int e = idx & 1023, p = idx >> 10;
        wxT[p * D_MODEL + e] = f2bf(wx[e * 96 + p]);
    } else if (blk < 5504) {  // wxBC[p][e] = w_x[e][64+p], p<32
        int idx = (blk - 5376) * 256 + t;
        int e = idx & 1023, p = idx >> 10;
        wxBC[p * D_MODEL + e] = f2bf(wx[e * 96 + 64 + p]);
    } else if (blk < 5568) {  // aneg (fp32, [d][n], pre-scaled by log2e) + anegT (bf16, [n][d], UNscaled)
        int i = (blk - 5504) * 256 + t;  // 64 blocks -> 16384 exact
        float v = -expf(alog[i]);
        aneg[i] = v * LOG2E;
        anegT[(i & 15) * D_MODEL + (i >> 4)] = f2bf(v);
    } else {  // wdtT[d][k] = w_dt[k][d] bf16  (256 blocks -> 65536)
        int idx = (blk - 5568) * 256 + t;
        int d = idx & 1023, k = idx >> 10;
        wdtT[d * DT_RANK + k] = f2bf(wdt[k * D_MODEL + d]);
    }
}

// ---------- x_in GEMM: x_in = x @ w_in. 64x128 tile, BK=64, dbuf, XOR-swizzle, grid 512 ----------
// XCD-aware bid remap: each XCD gets 8 m-panels x all 8 n-tiles (xb panel fetched once/XCD)
__global__ void __launch_bounds__(256) k_gemm_xin(const unsigned short* __restrict__ xb,
                                                  const unsigned short* __restrict__ bt,
                                                  unsigned short* __restrict__ xinb) {
    __shared__ unsigned short sA[2][64 * 64];
    __shared__ unsigned short sB[2][128 * 64];
    int bid0 = blockIdx.x;               // 512, XCD = bid0 % 8
    int bid = (bid0 & 7) * 64 + (bid0 >> 3);
    int m0 = (bid >> 3) * 64;            // m-major within XCD chunk
    int n0 = (bid & 7) * 128;
    int t = threadIdx.x;
    int lane = t & 63;
    int w = t >> 6;
    int wm = (w >> 1) * 32, wn = (w & 1) * 64;
    int c = lane & 15, q = lane >> 4;

    const unsigned short* gA[2];
    const unsigned short* gB[4];
#pragma unroll
    for (int L = 0; L < 2; L++) {
        int s = L * 256 + t;
        int row = s >> 3, ch = (s & 7) ^ (row & 7);
        gA[L] = xb + (m0 + row) * D_MODEL + ch * 8;
    }
#pragma unroll
    for (int L = 0; L < 4; L++) {
        int s = L * 256 + t;
        int row = s >> 3, ch = (s & 7) ^ (row & 7);
        gB[L] = bt + (n0 + row) * D_MODEL + ch * 8;
    }

    f32x4 acc[2][4] = {};
    {
        char* la = (char*)&sA[0][0] + w * 1024;
        char* lb = (char*)&sB[0][0] + w * 1024;
#pragma unroll
        for (int L = 0; L < 2; L++) gload16(gA[L], la + L * 4096);
#pragma unroll
        for (int L = 0; L < 4; L++) gload16(gB[L], lb + L * 4096);
    }
    int cur = 0;
    for (int it = 0; it < 16; it++) {
        __syncthreads();
        if (it + 1 < 16) {
            int kn = (it + 1) * 64;
            char* la = (char*)&sA[cur ^ 1][0] + w * 1024;
            char* lb = (char*)&sB[cur ^ 1][0] + w * 1024;
#pragma unroll
            for (int L = 0; L < 2; L++) gload16(gA[L] + kn, la + L * 4096);
#pragma unroll
            for (int L = 0; L < 4; L++) gload16(gB[L] + kn, lb + L * 4096);
        }
#pragma unroll
        for (int kk = 0; kk < 2; kk++) {
            int perm = (((kk << 2) | q) ^ (c & 7)) << 3;
            bf16x8 af[2], bfr[4];
#pragma unroll
            for (int i = 0; i < 2; i++)
                af[i] = *reinterpret_cast<const bf16x8*>(&sA[cur][(wm + i * 16 + c) * 64 + perm]);
#pragma unroll
            for (int j = 0; j < 4; j++)
                bfr[j] = *reinterpret_cast<const bf16x8*>(&sB[cur][(wn + j * 16 + c) * 64 + perm]);
            // swapped operands: lane owns 4 consecutive n-cols
#pragma unroll
            for (int i = 0; i < 2; i++)
#pragma unroll
                for (int j = 0; j < 4; j++)
                    acc[i][j] = __builtin_amdgcn_mfma_f32_16x16x32_bf16(bfr[j], af[i], acc[i][j], 0, 0, 0);
        }
        cur ^= 1;
    }
#pragma unroll
    for (int i = 0; i < 2; i++) {
        int row = m0 + wm + i * 16 + c;
#pragma unroll
        for (int j = 0; j < 4; j++) {
            int col = n0 + wn + j * 16 + q * 4;
            ushort4 o;
            o.x = f2bf(acc[i][j][0]); o.y = f2bf(acc[i][j][1]);
            o.z = f2bf(acc[i][j][2]); o.w = f2bf(acc[i][j][3]);
            *reinterpret_cast<ushort4*>(&xinb[row * D_MODEL + col]) = o;
        }
    }
}

// ---------- fused dt: per-block 16 rows. Wave-ksplit xlow (K=1024/4) -> LDS reduce ->
// ---------- bf16 tile -> dt = softplus(xlow @ w_dt + b). Replaces xlowp+xred+gemm_dt. ----------
__global__ void __launch_bounds__(256) k_dt2(const unsigned short* __restrict__ xinb,
                                             const unsigned short* __restrict__ wxT,
                                             const unsigned short* __restrict__ wdtT,
                                             const float* __restrict__ bdt,
                                             unsigned short* __restrict__ dtb) {
    __shared__ float sP[4][64][17];        // [wave][p][m], +1 pad kills bank conflicts
    __shared__ unsigned short sX[16 * 64]; // bf16 [m][p], XOR-swizzled 8-elem chunks
    int m0 = blockIdx.x * 16;              // 256 blocks x 16 rows
    int t = threadIdx.x;
    int lane = t & 63, w = t >> 6;
    int c = lane & 15, q = lane >> 4;

    // phase 1: partial xlow over K slice [w*256, w*256+256)  (mirrors k_xlowp)
    f32x4 acc[4] = {};
    const unsigned short* pa = xinb + (m0 + c) * D_MODEL + w * 256 + q * 8;
    const unsigned short* pw = wxT + c * D_MODEL + w * 256 + q * 8;
#pragma unroll
    for (int k0 = 0; k0 < 256; k0 += 32) {
        bf16x8 a0 = *reinterpret_cast<const bf16x8*>(pa + k0);
#pragma unroll
        for (int j = 0; j < 4; j++) {
            bf16x8 wf = *reinterpret_cast<const bf16x8*>(pw + j * 16 * D_MODEL + k0);
            acc[j] = __builtin_amdgcn_mfma_f32_16x16x32_bf16(wf, a0, acc[j], 0, 0, 0);
        }
    }
    // swapped C/D: lane col(c)=m-row, rows q*4+r = p
#pragma unroll
    for (int j = 0; j < 4; j++)
#pragma unroll
        for (int r = 0; r < 4; r++)
            sP[w][j * 16 + q * 4 + r][c] = acc[j][r];
    __syncthreads();

    // phase 2: reduce 4 wave-partials -> bf16 sX[m][p] (swizzled like k_gemm_dt's sA)
    {
        int m = t >> 4, col4 = t & 15;  // p-group col4*4..+4
        float s0 = 0.f, s1 = 0.f, s2 = 0.f, s3 = 0.f;
#pragma unroll
        for (int ww = 0; ww < 4; ww++) {
            s0 += sP[ww][col4 * 4 + 0][m];
            s1 += sP[ww][col4 * 4 + 1][m];
            s2 += sP[ww][col4 * 4 + 2][m];
            s3 += sP[ww][col4 * 4 + 3][m];
        }
        ushort4 o;
        o.x = f2bf(s0); o.y = f2bf(s1); o.z = f2bf(s2); o.w = f2bf(s3);
        int chunk = col4 >> 1, within = (col4 & 1) * 4;
        int swz = chunk ^ (m & 7);
        *reinterpret_cast<ushort4*>(&sX[m * 64 + swz * 8 + within]) = o;
    }
    __syncthreads();

    // phase 3: dt = softplus(xlow @ wdtT^T + b); wave w -> d-range [w*256, +256)
    bf16x8 af[2];
#pragma unroll
    for (int kk = 0; kk < 2; kk++) {
        int swz = (kk * 4 + q) ^ (c & 7);
        af[kk] = *reinterpret_cast<const bf16x8*>(&sX[c * 64 + swz * 8]);
    }
    int nbase = w * 256;
#pragma unroll 4
    for (int j = 0; j < 16; j++) {
        f32x4 a = {};
#pragma unroll
        for (int kk = 0; kk < 2; kk++) {
            bf16x8 bfr = *reinterpret_cast<const bf16x8*>(
                &wdtT[(nbase + j * 16 + c) * DT_RANK + kk * 32 + q * 8]);
            a = __builtin_amdgcn_mfma_f32_16x16x32_bf16(bfr, af[kk], a, 0, 0, 0);
        }
        int dcol = nbase + j * 16 + q * 4;
        float4 bv = *reinterpret_cast<const float4*>(&bdt[dcol]);
        ushort4 o;
        {
            float xv = a[0] + bv.x;
            float sp = fmaxf(xv, 0.f) + __logf(1.f + __expf(-fabsf(xv)));
            o.x = f2bf(sp * 0.099f + 0.001f);
        }
        {
            float xv = a[1] + bv.y;
            float sp = fmaxf(xv, 0.f) + __logf(1.f + __expf(-fabsf(xv)));
            o.y = f2bf(sp * 0.099f + 0.001f);
        }
        {
            float xv = a[2] + bv.z;
            float sp = fmaxf(xv, 0.f) + __logf(1.f + __expf(-fabsf(xv)));
            o.z = f2bf(sp * 0.099f + 0.001f);
        }
        {
            float xv = a[3] + bv.w;
            float sp = fmaxf(xv, 0.f) + __logf(1.f + __expf(-fabsf(xv)));
            o.w = f2bf(sp * 0.099f + 0.001f);
        }
        *reinterpret_cast<ushort4*>(&dtb[(m0 + c) * D_MODEL + dcol]) = o;
    }
}

// ---------- BCW GEMM: bcp = x_in @ wxBC^T ; wpp = (dt*u) @ anegT^T ; ksplit=8, grid 256 ----------
__global__ void __launch_bounds__(256) k_bcw(const unsigned short* __restrict__ xinb,
                                             const unsigned short* __restrict__ dtb,
                                             const unsigned short* __restrict__ wxBC,
                                             const unsigned short* __restrict__ anegT,
                                             float* __restrict__ bcp,
                                             float* __restrict__ wpp) {
    int bid = blockIdx.x;  // 256 = 32 mtiles x 8 ksplit
    int m0 = (bid & 31) * 128;
    int ks = bid >> 5;
    int kbase = ks * 128;
    int t = threadIdx.x;
    int lane = t & 63, w = t >> 6;
    int c = lane & 15, q = lane >> 4;
    int mw = m0 + w * 32;
    f32x4 accb[2][2] = {};
    f32x4 accw[2] = {};
    const unsigned short* pa0 = xinb + (mw + c) * D_MODEL + kbase + q * 8;
    const unsigned short* pa1 = pa0 + 16 * D_MODEL;
    const unsigned short* pt0 = dtb + (mw + c) * D_MODEL + kbase + q * 8;
    const unsigned short* pt1 = pt0 + 16 * D_MODEL;
    const unsigned short* pb0 = wxBC + c * D_MODEL + kbase + q * 8;
    const unsigned short* pb1 = pb0 + 16 * D_MODEL;
    const unsigned short* pA = anegT + c * D_MODEL + kbase + q * 8;
#pragma unroll
    for (int k0 = 0; k0 < 128; k0 += 32) {
        bf16x8 a0 = *reinterpret_cast<const bf16x8*>(pa0 + k0);
        bf16x8 a1 = *reinterpret_cast<const bf16x8*>(pa1 + k0);
        bf16x8 t0 = *reinterpret_cast<const bf16x8*>(pt0 + k0);
        bf16x8 t1 = *reinterpret_cast<const bf16x8*>(pt1 + k0);
        bf16x8 b0 = *reinterpret_cast<const bf16x8*>(pb0 + k0);
        bf16x8 b1 = *reinterpret_cast<const bf16x8*>(pb1 + k0);
        bf16x8 bA = *reinterpret_cast<const bf16x8*>(pA + k0);
        bf16x8 g0, g1;
#pragma unroll
        for (int e = 0; e < 8; e++) {
            g0[e] = (__bf16)((float)t0[e] * (float)a0[e]);
            g1[e] = (__bf16)((float)t1[e] * (float)a1[e]);
        }
        accb[0][0] = __builtin_amdgcn_mfma_f32_16x16x32_bf16(b0, a0, accb[0][0], 0, 0, 0);
        accb[0][1] = __builtin_amdgcn_mfma_f32_16x16x32_bf16(b1, a0, accb[0][1], 0, 0, 0);
        accb[1][0] = __builtin_amdgcn_mfma_f32_16x16x32_bf16(b0, a1, accb[1][0], 0, 0, 0);
        accb[1][1] = __builtin_amdgcn_mfma_f32_16x16x32_bf16(b1, a1, accb[1][1], 0, 0, 0);
        accw[0] = __builtin_amdgcn_mfma_f32_16x16x32_bf16(bA, g0, accw[0], 0, 0, 0);
        accw[1] = __builtin_amdgcn_mfma_f32_16x16x32_bf16(bA, g1, accw[1], 0, 0, 0);
    }
#pragma unroll
    for (int i = 0; i < 2; i++) {
        int row = mw + i * 16 + c;
#pragma unroll
        for (int j = 0; j < 2; j++)
            *reinterpret_cast<f32x4*>(&bcp[(ks * M_TOTAL + row) * 32 + j * 16 + q * 4]) = accb[i][j];
        *reinterpret_cast<f32x4*>(&wpp[(ks * M_TOTAL + row) * 16 + q * 4]) = accw[i];
    }
}

// ---------- scan phase 1: chunk-local scan -> h_loc, dtsum (XCD-swizzled bid) ----------
__global__ void __launch_bounds__(256) k_scan1(const unsigned short* __restrict__ dtb,
                                               const float* __restrict__ bcp,
                                               const float* __restrict__ wpp,
                                               const float* __restrict__ aneg,
                                               float* __restrict__ h_loc,
                                               float* __restrict__ dtsum) {
    __shared__ unsigned short s_dt[16][256];
    __shared__ float s_w[16][16];
    int bid0 = blockIdx.x;                      // 512; group dc-siblings per XCD
    int bid = (bid0 & 7) * 64 + (bid0 >> 3);
    int dc = bid & 3;
    int c = (bid >> 2) & (CHUNKS - 1);
    int b = bid >> 8;
    int tid = threadIdx.x;
    int d = dc * 256 + tid;
    float Ad[16];
    const float4* ar = reinterpret_cast<const float4*>(aneg + d * 16);
#pragma unroll
    for (int j = 0; j < 4; j++) {
        float4 a4 = ar[j];
        Ad[4 * j + 0] = a4.x; Ad[4 * j + 1] = a4.y;
        Ad[4 * j + 2] = a4.z; Ad[4 * j + 3] = a4.w;
    }
    float h[16];
#pragma unroll
    for (int n = 0; n < 16; n++) h[n] = 0.f;
    float dts = 0.f;

    int r8 = tid >> 5, col8 = (tid & 31) * 8;
    for (int t0 = 0; t0 < CLEN; t0 += 16) {
        __syncthreads();
        int rowbase = b * SEQ + c * CLEN + t0;
        *reinterpret_cast<uint4*>(&s_dt[r8][col8]) =
            *reinterpret_cast<const uint4*>(dtb + (rowbase + r8) * D_MODEL + dc * 256 + col8);
        *reinterpret_cast<uint4*>(&s_dt[8 + r8][col8]) =
            *reinterpret_cast<const uint4*>(dtb + (rowbase + 8 + r8) * D_MODEL + dc * 256 + col8);
        {
            int r = tid >> 4, n = tid & 15;
            int row = rowbase + r;
            float sB = 0.f, sw = 0.f;
#pragma unroll
            for (int ks = 0; ks < 8; ks++) {
                sB += bcp[(ks * M_TOTAL + row) * 32 + n];
                sw += wpp[(ks * M_TOTAL + row) * 16 + n];
            }
            s_w[r][n] = sB * sw;
        }
        __syncthreads();
        for (int r = 0; r < 16; r++) {
            float dtv = bf2f(s_dt[r][tid]);
            dts += dtv;
#pragma unroll
            for (int n = 0; n < 16; n++) {
                float ba = fexp2(dtv * Ad[n]);  // Ad pre-scaled by log2e
                h[n] = fmaf(ba, h[n], s_w[r][n]);
            }
        }
    }
    int base = ((b * CHUNKS + c) * D_MODEL + d) * 16;
#pragma unroll
    for (int j = 0; j < 4; j++) {
        f32x4 v = {h[4 * j], h[4 * j + 1], h[4 * j + 2], h[4 * j + 3]};
        *reinterpret_cast<f32x4*>(h_loc + base + 4 * j) = v;
    }
    dtsum[(b * CHUNKS + c) * D_MODEL + d] = dts;
}

// ---------- scan phase 2: combine chunks, 8-deep prefetch, 256 blocks x 128 thr ----------
__global__ void __launch_bounds__(128) k_scan2(float* __restrict__ h_inout,
                                               const float* __restrict__ dtsum,
                                               const float* __restrict__ aneg) {
    int idx = blockIdx.x * 128 + threadIdx.x;  // 32768
    int n = idx & 15;
    int d = (idx >> 4) & (D_MODEL - 1);
    int b = idx >> 14;
    float A = aneg[d * 16 + n];  // pre-scaled by log2e
    float H = 0.f;
    int off0 = b * CHUNKS * D_MODEL + d;
#pragma unroll 1
    for (int g = 0; g < CHUNKS; g += 8) {
        float hl[8], ds[8];
#pragma unroll
        for (int j = 0; j < 8; j++) {
            int off = off0 + (g + j) * D_MODEL;
            hl[j] = h_inout[off * 16 + n];
            ds[j] = dtsum[off];
        }
#pragma unroll
        for (int j = 0; j < 8; j++) {
            int off = off0 + (g + j) * D_MODEL;
            float P = fexp2(ds[j] * A);
            h_inout[off * 16 + n] = H;
            H = fmaf(P, H, hl[j]);
        }
    }
}

// ---------- scan phase 3: chunk scan from H_in; emit y (XCD-swizzled bid) ----------
__global__ void __launch_bounds__(256) k_scan3(const unsigned short* __restrict__ dtb,
                                               const unsigned short* __restrict__ xinb,
                                               const float* __restrict__ bcp,
                                               const float* __restrict__ wpp,
                                               const float* __restrict__ aneg,
                                               const float* __restrict__ dp,
                                               const float* __restrict__ H_in,
                                               float* __restrict__ out) {
    __shared__ unsigned short s_dt[16][256], s_u[16][256];
    __shared__ float s_w[16][16], s_c[16][16];
    int bid0 = blockIdx.x;                      // 512; group dc-siblings per XCD
    int bid = (bid0 & 7) * 64 + (bid0 >> 3);
    int dc = bid & 3;
    int c = (bid >> 2) & (CHUNKS - 1);
    int b = bid >> 8;
    int tid = threadIdx.x;
    int d = dc * 256 + tid;
    float Ad[16];
    const float4* ar = reinterpret_cast<const float4*>(aneg + d * 16);
#pragma unroll
    for (int j = 0; j < 4; j++) {
        float4 a4 = ar[j];
        Ad[4 * j + 0] = a4.x; Ad[4 * j + 1] = a4.y;
        Ad[4 * j + 2] = a4.z; Ad[4 * j + 3] = a4.w;
    }
    float Dpd = dp[d];
    float h[16];
    int base = ((b * CHUNKS + c) * D_MODEL + d) * 16;
#pragma unroll
    for (int j = 0; j < 4; j++) {
        f32x4 v = *reinterpret_cast<const f32x4*>(H_in + base + 4 * j);
        h[4 * j] = v[0]; h[4 * j + 1] = v[1]; h[4 * j + 2] = v[2]; h[4 * j + 3] = v[3];
    }

    int r8 = tid >> 5, col8 = (tid & 31) * 8;
    for (int t0 = 0; t0 < CLEN; t0 += 16) {
        __syncthreads();
        int rowbase = b * SEQ + c * CLEN + t0;
        *reinterpret_cast<uint4*>(&s_dt[r8][col8]) =
            *reinterpret_cast<const uint4*>(dtb + (rowbase + r8) * D_MODEL + dc * 256 + col8);
        *reinterpret_cast<uint4*>(&s_dt[8 + r8][col8]) =
            *reinterpret_cast<const uint4*>(dtb + (rowbase + 8 + r8) * D_MODEL + dc * 256 + col8);
        *reinterpret_cast<uint4*>(&s_u[r8][col8]) =
            *reinterpret_cast<const uint4*>(xinb + (rowbase + r8) * D_MODEL + dc * 256 + col8);
        *reinterpret_cast<uint4*>(&s_u[8 + r8][col8]) =
            *reinterpret_cast<const uint4*>(xinb + (rowbase + 8 + r8) * D_MODEL + dc * 256 + col8);
        {
            int r = tid >> 4, n = tid & 15;
            int row = rowbase + r;
            float sB = 0.f, sw = 0.f, sC = 0.f;
#pragma unroll
            for (int ks = 0; ks < 8; ks++) {
                sB += bcp[(ks * M_TOTAL + row) * 32 + n];
                sC += bcp[(ks * M_TOTAL + row) * 32 + 16 + n];
                sw += wpp[(ks * M_TOTAL + row) * 16 + n];
            }
            s_w[r][n] = sB * sw;
            s_c[r][n] = sC;
        }
        __syncthreads();
        for (int r = 0; r < 16; r++) {
            float dtv = bf2f(s_dt[r][tid]), uv = bf2f(s_u[r][tid]);
            float y = Dpd * uv;
#pragma unroll
            for (int n = 0; n < 16; n++) {
                float ba = fexp2(dtv * Ad[n]);  // Ad pre-scaled by log2e
                h[n] = fmaf(ba, h[n], s_w[r][n]);
                y = fmaf(h[n], s_c[r][n], y);
            }
            out[(rowbase + r) * D_MODEL + d] = y;
        }
    }
}

extern "C" void kernel_launch(void* const* d_in, const int* in_sizes, int n_in,
                              void* d_out, int out_size, void* d_ws, size_t ws_size,
                              hipStream_t stream) {
    const float* x     = (const float*)d_in[0];
    const float* w_in  = (const float*)d_in[1];
    const float* w_x   = (const float*)d_in[2];
    const float* w_dt  = (const float*)d_in[3];
    const float* b_dt  = (const float*)d_in[4];
    const float* A_log = (const float*)d_in[5];
    const float* Dp    = (const float*)d_in[6];
    float* out = (float*)d_out;

    char* ws = (char*)d_ws;
    // footprint capped below proven-safe 39124992 B
    unsigned short* xb   = (unsigned short*)(ws + 0);          // 8 MB  (dead after gemm_xin)
    unsigned short* bt   = (unsigned short*)(ws + 8388608);    // 2 MB  w_in^T (dead after gemm_xin)
    unsigned short* xinb = (unsigned short*)(ws + 10485760);   // 8 MB
    unsigned short* dtb  = (unsigned short*)(ws + 18874368);   // 8 MB
    float* bcp           = (float*)(ws + 27262976);            // 4 MB  -> ends 31457280
    float* wpp           = (float*)(ws + 31457280);            // 2 MB  -> ends 33554432
    unsigned short* wxT  = (unsigned short*)(ws + 35651584);   // 128 KB
    unsigned short* wxBC = (unsigned short*)(ws + 35782656);   // 64 KB
    unsigned short* wdtT = (unsigned short*)(ws + 35848192);   // 128 KB
    float* aneg          = (float*)(ws + 35979264);            // 64 KB (pre-scaled by log2e)
    unsigned short* anegT= (unsigned short*)(ws + 36044800);   // 32 KB -> ends 36077568
    // scan-phase overlays of dead xb/bt regions:
    float* h_loc         = (float*)(ws + 0);                   // 8 MB  [b][c][d][n]
    float* dtsum         = (float*)(ws + 8388608);             // 512 KB [b][c][d]

    k_setup<<<5824, 256, 0, stream>>>(x, w_in, w_x, w_dt, A_log, xb, bt, wxT, wxBC, wdtT, aneg, anegT);
    k_gemm_xin<<<512, 256, 0, stream>>>(xb, bt, xinb);
    k_dt2<<<256, 256, 0, stream>>>(xinb, wxT, wdtT, b_dt, dtb);
    k_bcw<<<256, 256, 0, stream>>>(xinb, dtb, wxBC, anegT, bcp, wpp);
    k_scan1<<<BATCH * CHUNKS * 4, 256, 0, stream>>>(dtb, bcp, wpp, aneg, h_loc, dtsum);
    k_scan2<<<256, 128, 0, stream>>>(h_loc, dtsum, aneg);
    k_scan3<<<BATCH * CHUNKS * 4, 256, 0, stream>>>(dtb, xinb, bcp, wpp, aneg, Dp, h_loc, out);
}

// Round 10
// 153.444 us; speedup vs baseline: 1.7971x; 1.0418x over previous
//
#include <hip/hip_runtime.h>
#include <hip/hip_bf16.h>

#define D_MODEL 1024
#define D_STATE 16
#define DT_RANK 64
#define SEQ 2048
#define BATCH 2
#define M_TOTAL 4096
#define CHUNKS 64
#define CLEN 32
#define LOG2E 1.44269504088896f

typedef __bf16 bf16x8 __attribute__((ext_vector_type(8)));
typedef float f32x4 __attribute__((ext_vector_type(4)));

__device__ __forceinline__ unsigned short f2bf(float f) {
    union { float f; unsigned int u; } v; v.f = f;
    unsigned int r = v.u + 0x7FFFu + ((v.u >> 16) & 1u);
    return (unsigned short)(r >> 16);
}
__device__ __forceinline__ float bf2f(unsigned short u) {
    union { unsigned int i; float f; } v; v.i = ((unsigned int)u) << 16; return v.f;
}
__device__ __forceinline__ void gload16(const void* g, void* l) {
    __builtin_amdgcn_global_load_lds(
        (const __attribute__((address_space(1))) unsigned int*)g,
        (__attribute__((address_space(3))) unsigned int*)l, 16, 0, 0);
}
__device__ __forceinline__ float fexp2(float x) { return __builtin_amdgcn_exp2f(x); }

// ---------- fused setup ----------
__global__ void __launch_bounds__(256) k_setup(const float* __restrict__ x,
                                               const float* __restrict__ win,
                                               const float* __restrict__ wx,
                                               const float* __restrict__ wdt,
                                               const float* __restrict__ alog,
                                               unsigned short* __restrict__ xb,
                                               unsigned short* __restrict__ bt,
                                               unsigned short* __restrict__ wxT,
                                               unsigned short* __restrict__ wxBC,
                                               unsigned short* __restrict__ wdtT,
                                               float* __restrict__ aneg,
                                               unsigned short* __restrict__ anegT) {
    __shared__ float tile[32][33];
    int blk = blockIdx.x;
    int t = threadIdx.x;
    if (blk < 4096) {  // x -> bf16
        int i = blk * 256 + t;
        float4 v = reinterpret_cast<const float4*>(x)[i];
        ushort4 o;
        o.x = f2bf(v.x); o.y = f2bf(v.y); o.z = f2bf(v.z); o.w = f2bf(v.w);
        reinterpret_cast<ushort4*>(xb)[i] = o;
    } else if (blk < 5120) {  // w_in^T -> bt
        int blk2 = blk - 4096;
        int bx = blk2 & 31, by = blk2 >> 5;
        int tx = t & 31, ty = t >> 5;
        int xc = bx * 32 + tx;
#pragma unroll
        for (int j = 0; j < 4; j++)
            tile[ty + 8 * j][tx] = win[(by * 32 + ty + 8 * j) * D_MODEL + xc];
        __syncthreads();
        int x2 = by * 32 + tx;
#pragma unroll
        for (int j = 0; j < 4; j++)
            bt[(bx * 32 + ty + 8 * j) * D_MODEL + x2] = f2bf(tile[tx][ty + 8 * j]);
    } else if (blk < 5376) {  // wxT[p][e] = w_x[e][p], p<64
        int idx = (blk - 5120) * 256 + t;
        int e = idx & 1023, p = idx >> 10;
        wxT[p * D_MODEL + e] = f2bf(wx[e * 96 + p]);
    } else if (blk < 5504) {  // wxBC[p][e] = w_x[e][64+p], p<32
        int idx = (blk - 5376) * 256 + t;
        int e = idx & 1023, p = idx >> 10;
        wxBC[p * D_MODEL + e] = f2bf(wx[e * 96 + 64 + p]);
    } else if (blk < 5568) {  // aneg (fp32, [d][n], pre-scaled by log2e) + anegT (bf16, [n][d], UNscaled)
        int i = (blk - 5504) * 256 + t;  // 64 blocks -> 16384 exact
        float v = -expf(alog[i]);
        aneg[i] = v * LOG2E;
        anegT[(i & 15) * D_MODEL + (i >> 4)] = f2bf(v);
    } else {  // wdtT[d][k] = w_dt[k][d] bf16  (256 blocks -> 65536)
        int idx = (blk - 5568) * 256 + t;
        int d = idx & 1023, k = idx >> 10;
        wdtT[d * DT_RANK + k] = f2bf(wdt[k * D_MODEL + d]);
    }
}

// ---------- x_in GEMM: x_in = x @ w_in. 64x128 tile, BK=64, dbuf, XOR-swizzle, grid 512 ----------
// XCD-aware bid remap: each XCD gets 8 m-panels x all 8 n-tiles (xb panel fetched once/XCD)
__global__ void __launch_bounds__(256) k_gemm_xin(const unsigned short* __restrict__ xb,
                                                  const unsigned short* __restrict__ bt,
                                                  unsigned short* __restrict__ xinb) {
    __shared__ unsigned short sA[2][64 * 64];
    __shared__ unsigned short sB[2][128 * 64];
    int bid0 = blockIdx.x;               // 512, XCD = bid0 % 8
    int bid = (bid0 & 7) * 64 + (bid0 >> 3);
    int m0 = (bid >> 3) * 64;            // m-major within XCD chunk
    int n0 = (bid & 7) * 128;
    int t = threadIdx.x;
    int lane = t & 63;
    int w = t >> 6;
    int wm = (w >> 1) * 32, wn = (w & 1) * 64;
    int c = lane & 15, q = lane >> 4;

    const unsigned short* gA[2];
    const unsigned short* gB[4];
#pragma unroll
    for (int L = 0; L < 2; L++) {
        int s = L * 256 + t;
        int row = s >> 3, ch = (s & 7) ^ (row & 7);
        gA[L] = xb + (m0 + row) * D_MODEL + ch * 8;
    }
#pragma unroll
    for (int L = 0; L < 4; L++) {
        int s = L * 256 + t;
        int row = s >> 3, ch = (s & 7) ^ (row & 7);
        gB[L] = bt + (n0 + row) * D_MODEL + ch * 8;
    }

    f32x4 acc[2][4] = {};
    {
        char* la = (char*)&sA[0][0] + w * 1024;
        char* lb = (char*)&sB[0][0] + w * 1024;
#pragma unroll
        for (int L = 0; L < 2; L++) gload16(gA[L], la + L * 4096);
#pragma unroll
        for (int L = 0; L < 4; L++) gload16(gB[L], lb + L * 4096);
    }
    int cur = 0;
    for (int it = 0; it < 16; it++) {
        __syncthreads();
        if (it + 1 < 16) {
            int kn = (it + 1) * 64;
            char* la = (char*)&sA[cur ^ 1][0] + w * 1024;
            char* lb = (char*)&sB[cur ^ 1][0] + w * 1024;
#pragma unroll
            for (int L = 0; L < 2; L++) gload16(gA[L] + kn, la + L * 4096);
#pragma unroll
            for (int L = 0; L < 4; L++) gload16(gB[L] + kn, lb + L * 4096);
        }
#pragma unroll
        for (int kk = 0; kk < 2; kk++) {
            int perm = (((kk << 2) | q) ^ (c & 7)) << 3;
            bf16x8 af[2], bfr[4];
#pragma unroll
            for (int i = 0; i < 2; i++)
                af[i] = *reinterpret_cast<const bf16x8*>(&sA[cur][(wm + i * 16 + c) * 64 + perm]);
#pragma unroll
            for (int j = 0; j < 4; j++)
                bfr[j] = *reinterpret_cast<const bf16x8*>(&sB[cur][(wn + j * 16 + c) * 64 + perm]);
            // swapped operands: lane owns 4 consecutive n-cols
#pragma unroll
            for (int i = 0; i < 2; i++)
#pragma unroll
                for (int j = 0; j < 4; j++)
                    acc[i][j] = __builtin_amdgcn_mfma_f32_16x16x32_bf16(bfr[j], af[i], acc[i][j], 0, 0, 0);
        }
        cur ^= 1;
    }
#pragma unroll
    for (int i = 0; i < 2; i++) {
        int row = m0 + wm + i * 16 + c;
#pragma unroll
        for (int j = 0; j < 4; j++) {
            int col = n0 + wn + j * 16 + q * 4;
            ushort4 o;
            o.x = f2bf(acc[i][j][0]); o.y = f2bf(acc[i][j][1]);
            o.z = f2bf(acc[i][j][2]); o.w = f2bf(acc[i][j][3]);
            *reinterpret_cast<ushort4*>(&xinb[row * D_MODEL + col]) = o;
        }
    }
}

// ---------- fused dt+BCW: per-block 16 rows.
// phase 1-3 = proven k_dt2 (xlow wave-ksplit -> LDS reduce -> dt GEMM -> dtb).
// phase 4-5 = bcw for the SAME 16 rows (wave-ksplit K=256, LDS reduce) -> FINAL winp/bcC.
__global__ void __launch_bounds__(256) k_dtbcw(const unsigned short* __restrict__ xinb,
                                               const unsigned short* __restrict__ wxT,
                                               const unsigned short* __restrict__ wdtT,
                                               const float* __restrict__ bdt,
                                               const unsigned short* __restrict__ wxBC,
                                               const unsigned short* __restrict__ anegT,
                                               unsigned short* __restrict__ dtb,
                                               float* __restrict__ winp,
                                               float* __restrict__ bcC) {
    __shared__ float sP[4][64][17];        // xlow wave partials, +1 pad
    __shared__ unsigned short sX[16 * 64]; // bf16 xlow tile, XOR-swizzled
    __shared__ float sBC[4][16][49];       // bcw wave partials: [w][row][p<32 | 32+n], +1 pad
    int m0 = blockIdx.x * 16;              // 256 blocks x 16 rows
    int t = threadIdx.x;
    int lane = t & 63, w = t >> 6;
    int c = lane & 15, q = lane >> 4;

    // phase 1: partial xlow over K slice [w*256, +256)
    {
        f32x4 acc[4] = {};
        const unsigned short* pa = xinb + (m0 + c) * D_MODEL + w * 256 + q * 8;
        const unsigned short* pw = wxT + c * D_MODEL + w * 256 + q * 8;
#pragma unroll
        for (int k0 = 0; k0 < 256; k0 += 32) {
            bf16x8 a0 = *reinterpret_cast<const bf16x8*>(pa + k0);
#pragma unroll
            for (int j = 0; j < 4; j++) {
                bf16x8 wf = *reinterpret_cast<const bf16x8*>(pw + j * 16 * D_MODEL + k0);
                acc[j] = __builtin_amdgcn_mfma_f32_16x16x32_bf16(wf, a0, acc[j], 0, 0, 0);
            }
        }
        // swapped C/D: lane col(c)=m-row, rows q*4+r = p
#pragma unroll
        for (int j = 0; j < 4; j++)
#pragma unroll
            for (int r = 0; r < 4; r++)
                sP[w][j * 16 + q * 4 + r][c] = acc[j][r];
    }
    __syncthreads();

    // phase 2: reduce 4 wave-partials -> bf16 sX[m][p] (swizzled)
    {
        int m = t >> 4, col4 = t & 15;
        float s0 = 0.f, s1 = 0.f, s2 = 0.f, s3 = 0.f;
#pragma unroll
        for (int ww = 0; ww < 4; ww++) {
            s0 += sP[ww][col4 * 4 + 0][m];
            s1 += sP[ww][col4 * 4 + 1][m];
            s2 += sP[ww][col4 * 4 + 2][m];
            s3 += sP[ww][col4 * 4 + 3][m];
        }
        ushort4 o;
        o.x = f2bf(s0); o.y = f2bf(s1); o.z = f2bf(s2); o.w = f2bf(s3);
        int chunk = col4 >> 1, within = (col4 & 1) * 4;
        int swz = chunk ^ (m & 7);
        *reinterpret_cast<ushort4*>(&sX[m * 64 + swz * 8 + within]) = o;
    }
    __syncthreads();

    // phase 3: dt = softplus(xlow @ wdtT^T + b); wave w -> d-range [w*256, +256); write dtb
    {
        bf16x8 af[2];
#pragma unroll
        for (int kk = 0; kk < 2; kk++) {
            int swz = (kk * 4 + q) ^ (c & 7);
            af[kk] = *reinterpret_cast<const bf16x8*>(&sX[c * 64 + swz * 8]);
        }
        int nbase = w * 256;
#pragma unroll 4
        for (int j = 0; j < 16; j++) {
            f32x4 a = {};
#pragma unroll
            for (int kk = 0; kk < 2; kk++) {
                bf16x8 bfr = *reinterpret_cast<const bf16x8*>(
                    &wdtT[(nbase + j * 16 + c) * DT_RANK + kk * 32 + q * 8]);
                a = __builtin_amdgcn_mfma_f32_16x16x32_bf16(bfr, af[kk], a, 0, 0, 0);
            }
            int dcol = nbase + j * 16 + q * 4;
            float4 bv = *reinterpret_cast<const float4*>(&bdt[dcol]);
            ushort4 o;
            {
                float xv = a[0] + bv.x;
                float sp = fmaxf(xv, 0.f) + __logf(1.f + __expf(-fabsf(xv)));
                o.x = f2bf(sp * 0.099f + 0.001f);
            }
            {
                float xv = a[1] + bv.y;
                float sp = fmaxf(xv, 0.f) + __logf(1.f + __expf(-fabsf(xv)));
                o.y = f2bf(sp * 0.099f + 0.001f);
            }
            {
                float xv = a[2] + bv.z;
                float sp = fmaxf(xv, 0.f) + __logf(1.f + __expf(-fabsf(xv)));
                o.z = f2bf(sp * 0.099f + 0.001f);
            }
            {
                float xv = a[3] + bv.w;
                float sp = fmaxf(xv, 0.f) + __logf(1.f + __expf(-fabsf(xv)));
                o.w = f2bf(sp * 0.099f + 0.001f);
            }
            *reinterpret_cast<ushort4*>(&dtb[(m0 + c) * D_MODEL + dcol]) = o;
        }
    }
    __syncthreads();  // drains vmcnt: dtb writes visible to same-CU reads below

    // phase 4: bcw partials for the same 16 rows, K-slice [w*256, +256).
    // wave w reads back the dtb slice wave w itself wrote (same CU -> same L1, safe).
    {
        f32x4 accb[2] = {};
        f32x4 accw = {};
        const unsigned short* pa = xinb + (m0 + c) * D_MODEL + w * 256 + q * 8;
        const unsigned short* pt = dtb + (m0 + c) * D_MODEL + w * 256 + q * 8;
        const unsigned short* pb0 = wxBC + c * D_MODEL + w * 256 + q * 8;
        const unsigned short* pb1 = pb0 + 16 * D_MODEL;
        const unsigned short* pA = anegT + c * D_MODEL + w * 256 + q * 8;
#pragma unroll
        for (int k0 = 0; k0 < 256; k0 += 32) {
            bf16x8 a0 = *reinterpret_cast<const bf16x8*>(pa + k0);
            bf16x8 t0 = *reinterpret_cast<const bf16x8*>(pt + k0);
            bf16x8 b0 = *reinterpret_cast<const bf16x8*>(pb0 + k0);
            bf16x8 b1 = *reinterpret_cast<const bf16x8*>(pb1 + k0);
            bf16x8 bA = *reinterpret_cast<const bf16x8*>(pA + k0);
            bf16x8 g0;
#pragma unroll
            for (int e = 0; e < 8; e++) g0[e] = (__bf16)((float)t0[e] * (float)a0[e]);
            accb[0] = __builtin_amdgcn_mfma_f32_16x16x32_bf16(b0, a0, accb[0], 0, 0, 0);
            accb[1] = __builtin_amdgcn_mfma_f32_16x16x32_bf16(b1, a0, accb[1], 0, 0, 0);
            accw = __builtin_amdgcn_mfma_f32_16x16x32_bf16(bA, g0, accw, 0, 0, 0);
        }
        // swapped C/D: lane col(c) = row, reg rows q*4+r = p (or n)
#pragma unroll
        for (int j = 0; j < 2; j++)
#pragma unroll
            for (int r = 0; r < 4; r++)
                sBC[w][c][j * 16 + q * 4 + r] = accb[j][r];
#pragma unroll
        for (int r = 0; r < 4; r++)
            sBC[w][c][32 + q * 4 + r] = accw[r];
    }
    __syncthreads();

    // phase 5: reduce 4 wave-partials -> FINAL winp = sB*sW, bcC  (256 thr = 16 rows x 16 n)
    {
        int row = t >> 4, n = t & 15;
        float sB = 0.f, sC = 0.f, sW = 0.f;
#pragma unroll
        for (int ww = 0; ww < 4; ww++) {
            sB += sBC[ww][row][n];
            sC += sBC[ww][row][16 + n];
            sW += sBC[ww][row][32 + n];
        }
        winp[(m0 + row) * 16 + n] = sB * sW;
        bcC[(m0 + row) * 16 + n] = sC;
    }
}

// ---------- scan phase 1: chunk-local scan -> h_loc, dtsum (XCD-swizzled; single winp read) ----------
__global__ void __launch_bounds__(256) k_scan1(const unsigned short* __restrict__ dtb,
                                               const float* __restrict__ winp,
                                               const float* __restrict__ aneg,
                                               float* __restrict__ h_loc,
                                               float* __restrict__ dtsum) {
    __shared__ unsigned short s_dt[16][256];
    __shared__ float s_w[16][16];
    int bid0 = blockIdx.x;                      // 512; group dc-siblings per XCD
    int bid = (bid0 & 7) * 64 + (bid0 >> 3);
    int dc = bid & 3;
    int c = (bid >> 2) & (CHUNKS - 1);
    int b = bid >> 8;
    int tid = threadIdx.x;
    int d = dc * 256 + tid;
    float Ad[16];
    const float4* ar = reinterpret_cast<const float4*>(aneg + d * 16);
#pragma unroll
    for (int j = 0; j < 4; j++) {
        float4 a4 = ar[j];
        Ad[4 * j + 0] = a4.x; Ad[4 * j + 1] = a4.y;
        Ad[4 * j + 2] = a4.z; Ad[4 * j + 3] = a4.w;
    }
    float h[16];
#pragma unroll
    for (int n = 0; n < 16; n++) h[n] = 0.f;
    float dts = 0.f;

    int r8 = tid >> 5, col8 = (tid & 31) * 8;
    for (int t0 = 0; t0 < CLEN; t0 += 16) {
        __syncthreads();
        int rowbase = b * SEQ + c * CLEN + t0;
        *reinterpret_cast<uint4*>(&s_dt[r8][col8]) =
            *reinterpret_cast<const uint4*>(dtb + (rowbase + r8) * D_MODEL + dc * 256 + col8);
        *reinterpret_cast<uint4*>(&s_dt[8 + r8][col8]) =
            *reinterpret_cast<const uint4*>(dtb + (rowbase + 8 + r8) * D_MODEL + dc * 256 + col8);
        {
            int r = tid >> 4, n = tid & 15;
            s_w[r][n] = winp[(rowbase + r) * 16 + n];  // coalesced: addr = rowbase*16 + tid
        }
        __syncthreads();
        for (int r = 0; r < 16; r++) {
            float dtv = bf2f(s_dt[r][tid]);
            dts += dtv;
#pragma unroll
            for (int n = 0; n < 16; n++) {
                float ba = fexp2(dtv * Ad[n]);  // Ad pre-scaled by log2e
                h[n] = fmaf(ba, h[n], s_w[r][n]);
            }
        }
    }
    int base = ((b * CHUNKS + c) * D_MODEL + d) * 16;
#pragma unroll
    for (int j = 0; j < 4; j++) {
        f32x4 v = {h[4 * j], h[4 * j + 1], h[4 * j + 2], h[4 * j + 3]};
        *reinterpret_cast<f32x4*>(h_loc + base + 4 * j) = v;
    }
    dtsum[(b * CHUNKS + c) * D_MODEL + d] = dts;
}

// ---------- scan phase 2: combine chunks, 8-deep prefetch, 256 blocks x 128 thr ----------
__global__ void __launch_bounds__(128) k_scan2(float* __restrict__ h_inout,
                                               const float* __restrict__ dtsum,
                                               const float* __restrict__ aneg) {
    int idx = blockIdx.x * 128 + threadIdx.x;  // 32768
    int n = idx & 15;
    int d = (idx >> 4) & (D_MODEL - 1);
    int b = idx >> 14;
    float A = aneg[d * 16 + n];  // pre-scaled by log2e
    float H = 0.f;
    int off0 = b * CHUNKS * D_MODEL + d;
#pragma unroll 1
    for (int g = 0; g < CHUNKS; g += 8) {
        float hl[8], ds[8];
#pragma unroll
        for (int j = 0; j < 8; j++) {
            int off = off0 + (g + j) * D_MODEL;
            hl[j] = h_inout[off * 16 + n];
            ds[j] = dtsum[off];
        }
#pragma unroll
        for (int j = 0; j < 8; j++) {
            int off = off0 + (g + j) * D_MODEL;
            float P = fexp2(ds[j] * A);
            h_inout[off * 16 + n] = H;
            H = fmaf(P, H, hl[j]);
        }
    }
}

// ---------- scan phase 3: chunk scan from H_in; emit y (XCD-swizzled; single winp/bcC reads) ----------
__global__ void __launch_bounds__(256) k_scan3(const unsigned short* __restrict__ dtb,
                                               const unsigned short* __restrict__ xinb,
                                               const float* __restrict__ winp,
                                               const float* __restrict__ bcC,
                                               const float* __restrict__ aneg,
                                               const float* __restrict__ dp,
                                               const float* __restrict__ H_in,
                                               float* __restrict__ out) {
    __shared__ unsigned short s_dt[16][256], s_u[16][256];
    __shared__ float s_w[16][16], s_c[16][16];
    int bid0 = blockIdx.x;                      // 512; group dc-siblings per XCD
    int bid = (bid0 & 7) * 64 + (bid0 >> 3);
    int dc = bid & 3;
    int c = (bid >> 2) & (CHUNKS - 1);
    int b = bid >> 8;
    int tid = threadIdx.x;
    int d = dc * 256 + tid;
    float Ad[16];
    const float4* ar = reinterpret_cast<const float4*>(aneg + d * 16);
#pragma unroll
    for (int j = 0; j < 4; j++) {
        float4 a4 = ar[j];
        Ad[4 * j + 0] = a4.x; Ad[4 * j + 1] = a4.y;
        Ad[4 * j + 2] = a4.z; Ad[4 * j + 3] = a4.w;
    }
    float Dpd = dp[d];
    float h[16];
    int base = ((b * CHUNKS + c) * D_MODEL + d) * 16;
#pragma unroll
    for (int j = 0; j < 4; j++) {
        f32x4 v = *reinterpret_cast<const f32x4*>(H_in + base + 4 * j);
        h[4 * j] = v[0]; h[4 * j + 1] = v[1]; h[4 * j + 2] = v[2]; h[4 * j + 3] = v[3];
    }

    int r8 = tid >> 5, col8 = (tid & 31) * 8;
    for (int t0 = 0; t0 < CLEN; t0 += 16) {
        __syncthreads();
        int rowbase = b * SEQ + c * CLEN + t0;
        *reinterpret_cast<uint4*>(&s_dt[r8][col8]) =
            *reinterpret_cast<const uint4*>(dtb + (rowbase + r8) * D_MODEL + dc * 256 + col8);
        *reinterpret_cast<uint4*>(&s_dt[8 + r8][col8]) =
            *reinterpret_cast<const uint4*>(dtb + (rowbase + 8 + r8) * D_MODEL + dc * 256 + col8);
        *reinterpret_cast<uint4*>(&s_u[r8][col8]) =
            *reinterpret_cast<const uint4*>(xinb + (rowbase + r8) * D_MODEL + dc * 256 + col8);
        *reinterpret_cast<uint4*>(&s_u[8 + r8][col8]) =
            *reinterpret_cast<const uint4*>(xinb + (rowbase + 8 + r8) * D_MODEL + dc * 256 + col8);
        {
            int r = tid >> 4, n = tid & 15;
            s_w[r][n] = winp[(rowbase + r) * 16 + n];
            s_c[r][n] = bcC[(rowbase + r) * 16 + n];
        }
        __syncthreads();
        for (int r = 0; r < 16; r++) {
            float dtv = bf2f(s_dt[r][tid]), uv = bf2f(s_u[r][tid]);
            float y = Dpd * uv;
#pragma unroll
            for (int n = 0; n < 16; n++) {
                float ba = fexp2(dtv * Ad[n]);  // Ad pre-scaled by log2e
                h[n] = fmaf(ba, h[n], s_w[r][n]);
                y = fmaf(h[n], s_c[r][n], y);
            }
            out[(rowbase + r) * D_MODEL + d] = y;
        }
    }
}

extern "C" void kernel_launch(void* const* d_in, const int* in_sizes, int n_in,
                              void* d_out, int out_size, void* d_ws, size_t ws_size,
                              hipStream_t stream) {
    const float* x     = (const float*)d_in[0];
    const float* w_in  = (const float*)d_in[1];
    const float* w_x   = (const float*)d_in[2];
    const float* w_dt  = (const float*)d_in[3];
    const float* b_dt  = (const float*)d_in[4];
    const float* A_log = (const float*)d_in[5];
    const float* Dp    = (const float*)d_in[6];
    float* out = (float*)d_out;

    char* ws = (char*)d_ws;
    // footprint capped below proven-safe 39124992 B
    unsigned short* xb   = (unsigned short*)(ws + 0);          // 8 MB  (dead after gemm_xin)
    unsigned short* bt   = (unsigned short*)(ws + 8388608);    // 2 MB  w_in^T (dead after gemm_xin)
    unsigned short* xinb = (unsigned short*)(ws + 10485760);   // 8 MB
    unsigned short* dtb  = (unsigned short*)(ws + 18874368);   // 8 MB -> ends 27262976
    float* winp          = (float*)(ws + 27262976);            // 256 KB -> 27525120
    float* bcC           = (float*)(ws + 27525120);            // 256 KB -> 27787264
    unsigned short* wxT  = (unsigned short*)(ws + 35651584);   // 128 KB
    unsigned short* wxBC = (unsigned short*)(ws + 35782656);   // 64 KB
    unsigned short* wdtT = (unsigned short*)(ws + 35848192);   // 128 KB
    float* aneg          = (float*)(ws + 35979264);            // 64 KB (pre-scaled by log2e)
    unsigned short* anegT= (unsigned short*)(ws + 36044800);   // 32 KB -> ends 36077568
    // scan-phase overlays of dead xb/bt regions:
    float* h_loc         = (float*)(ws + 0);                   // 8 MB  [b][c][d][n]
    float* dtsum         = (float*)(ws + 8388608);             // 512 KB [b][c][d]

    k_setup<<<5824, 256, 0, stream>>>(x, w_in, w_x, w_dt, A_log, xb, bt, wxT, wxBC, wdtT, aneg, anegT);
    k_gemm_xin<<<512, 256, 0, stream>>>(xb, bt, xinb);
    k_dtbcw<<<256, 256, 0, stream>>>(xinb, wxT, wdtT, b_dt, wxBC, anegT, dtb, winp, bcC);
    k_scan1<<<BATCH * CHUNKS * 4, 256, 0, stream>>>(dtb, winp, aneg, h_loc, dtsum);
    k_scan2<<<256, 128, 0, stream>>>(h_loc, dtsum, aneg);
    k_scan3<<<BATCH * CHUNKS * 4, 256, 0, stream>>>(dtb, xinb, winp, bcC, aneg, Dp, h_loc, out);
}